// Round 1
// baseline (4718.321 us; speedup 1.0000x reference)
//
#include <hip/hip_runtime.h>
#include <hip/hip_bf16.h>
#include <math.h>

// Problem constants (fixed by setup_inputs)
#define Hdim 1024
#define Bsz  2
#define Slen 4096
#define Pn   256
#define NLAY 4

__device__ __forceinline__ float gelu_exact(float x) {
  return 0.5f * x * (1.0f + erff(x * 0.70710678118654752f));
}

// ---------------- embedding gather: x[row,:] = emb[seq[row],:] ----------------
__global__ void embed_kernel(const int* __restrict__ seq, const float* __restrict__ emb,
                             float* __restrict__ x) {
  int row = blockIdx.x;
  int tid = threadIdx.x;
  int tok = seq[row];
  float4 v = *(const float4*)(emb + (size_t)tok * Hdim + tid * 4);
  *(float4*)(x + (size_t)row * Hdim + tid * 4) = v;
}

// ---------------- patch id: pid[b,s] = min(#bd<=s, P-1) ----------------
__global__ void pid_kernel(const int* __restrict__ bounds, int* __restrict__ pid) {
  int i = blockIdx.x * 256 + threadIdx.x;      // 0 .. B*S-1
  int b = i >> 12;
  int s = i & (Slen - 1);
  const int* bd = bounds + b * Pn;
  int lo = 0, hi = Pn;
  while (lo < hi) { int m = (lo + hi) >> 1; if (bd[m] <= s) lo = m + 1; else hi = m; }
  pid[i] = min(lo, Pn - 1);
}

// ---------------- patch mean pooling (deterministic, contiguous ranges) ----------------
__global__ void pool_kernel(const float* __restrict__ x, const int* __restrict__ pid,
                            float* __restrict__ patches) {
  int bp = blockIdx.x;                 // b*Pn + p
  int b = bp >> 8;
  int p = bp & (Pn - 1);
  const int* pv = pid + b * Slen;
  int lo = 0, hi = Slen;
  while (lo < hi) { int m = (lo + hi) >> 1; if (pv[m] < p) lo = m + 1; else hi = m; }
  int start = lo;
  lo = 0; hi = Slen;
  while (lo < hi) { int m = (lo + hi) >> 1; if (pv[m] < p + 1) lo = m + 1; else hi = m; }
  int end = lo;
  int tid = threadIdx.x;
  float4 acc = {0.f, 0.f, 0.f, 0.f};
  for (int s = start; s < end; ++s) {
    float4 xv = *(const float4*)(x + ((size_t)(b * Slen + s)) * Hdim + tid * 4);
    acc.x += xv.x; acc.y += xv.y; acc.z += xv.z; acc.w += xv.w;
  }
  float cnt = (float)(end - start);
  float r = 1.0f / fmaxf(cnt, 1.0f);
  float4 o = {acc.x * r, acc.y * r, acc.z * r, acc.w * r};
  *(float4*)(patches + (size_t)bp * Hdim + tid * 4) = o;
}

// ---------------- LayerNorm: one block (256 thr) per row of length H ----------------
__global__ void ln_kernel(const float* __restrict__ in, const float* __restrict__ g,
                          const float* __restrict__ bvec, float* __restrict__ out) {
  int row = blockIdx.x;
  int tid = threadIdx.x;
  const float* xr = in + (size_t)row * Hdim;
  float4 v = *(const float4*)(xr + tid * 4);
  float s  = v.x + v.y + v.z + v.w;
  float ss = v.x * v.x + v.y * v.y + v.z * v.z + v.w * v.w;
#pragma unroll
  for (int off = 32; off; off >>= 1) { s += __shfl_xor(s, off); ss += __shfl_xor(ss, off); }
  __shared__ float rs[4], rss[4];
  int wid = tid >> 6;
  if ((tid & 63) == 0) { rs[wid] = s; rss[wid] = ss; }
  __syncthreads();
  float tot  = rs[0] + rs[1] + rs[2] + rs[3];
  float tot2 = rss[0] + rss[1] + rss[2] + rss[3];
  float mu = tot * (1.0f / Hdim);
  float var = tot2 * (1.0f / Hdim) - mu * mu;
  float rstd = rsqrtf(var + 1e-6f);
  float4 gg = *(const float4*)(g + tid * 4);
  float4 bb = *(const float4*)(bvec + tid * 4);
  float4 r;
  r.x = (v.x - mu) * rstd * gg.x + bb.x;
  r.y = (v.y - mu) * rstd * gg.y + bb.y;
  r.z = (v.z - mu) * rstd * gg.z + bb.z;
  r.w = (v.w - mu) * rstd * gg.w + bb.w;
  *(float4*)(out + (size_t)row * Hdim + tid * 4) = r;
}

// ---------------- generic tiled f32 GEMM: C = A[M,K]@B[K,N] + bias (+epilogue) ----------------
// EPI: 0 = bias only, 1 = bias+gelu, 2 = bias+residual(res)
#define BM 64
#define BN 64
#define BK 16

template<int EPI>
__launch_bounds__(256)
__global__ void gemm_kernel(const float* __restrict__ A, int lda,
                            const float* __restrict__ Bm, int ldb,
                            const float* __restrict__ bias,
                            const float* __restrict__ res,
                            float* __restrict__ C, int ldc, int K) {
  __shared__ float As[BK][BM + 4];   // +4 keeps 16B alignment, breaks pow2 stride
  __shared__ float Bs[BK][BN];
  int tid = threadIdx.x;
  int tx = tid & 15, ty = tid >> 4;
  int n0 = blockIdx.x * BN, m0 = blockIdx.y * BM;
  const float* Ap = A + (size_t)m0 * lda;
  const float* Bp = Bm + n0;
  int la_m = tid >> 2;
  int la_k = (tid & 3) * 4;
  int lb_k = tid >> 4;
  int lb_n = (tid & 15) * 4;
  float acc[4][4] = {};
  for (int k0 = 0; k0 < K; k0 += BK) {
    float4 av = *(const float4*)(Ap + (size_t)la_m * lda + k0 + la_k);
    float4 bv = *(const float4*)(Bp + (size_t)(k0 + lb_k) * ldb + lb_n);
    As[la_k + 0][la_m] = av.x;
    As[la_k + 1][la_m] = av.y;
    As[la_k + 2][la_m] = av.z;
    As[la_k + 3][la_m] = av.w;
    *(float4*)&Bs[lb_k][lb_n] = bv;
    __syncthreads();
#pragma unroll
    for (int kk = 0; kk < BK; ++kk) {
      float4 a = *(const float4*)&As[kk][ty * 4];
      float4 b = *(const float4*)&Bs[kk][tx * 4];
      acc[0][0] += a.x * b.x; acc[0][1] += a.x * b.y; acc[0][2] += a.x * b.z; acc[0][3] += a.x * b.w;
      acc[1][0] += a.y * b.x; acc[1][1] += a.y * b.y; acc[1][2] += a.y * b.z; acc[1][3] += a.y * b.w;
      acc[2][0] += a.z * b.x; acc[2][1] += a.z * b.y; acc[2][2] += a.z * b.z; acc[2][3] += a.z * b.w;
      acc[3][0] += a.w * b.x; acc[3][1] += a.w * b.y; acc[3][2] += a.w * b.z; acc[3][3] += a.w * b.w;
    }
    __syncthreads();
  }
  float4 bs = *(const float4*)(bias + n0 + tx * 4);
#pragma unroll
  for (int i = 0; i < 4; i++) {
    int m = m0 + ty * 4 + i;
    float4 r;
    r.x = acc[i][0] + bs.x;
    r.y = acc[i][1] + bs.y;
    r.z = acc[i][2] + bs.z;
    r.w = acc[i][3] + bs.w;
    if (EPI == 1) {
      r.x = gelu_exact(r.x); r.y = gelu_exact(r.y); r.z = gelu_exact(r.z); r.w = gelu_exact(r.w);
    }
    if (EPI == 2) {
      float4 rv = *(const float4*)(res + (size_t)m * ldc + n0 + tx * 4);
      r.x += rv.x; r.y += rv.y; r.z += rv.z; r.w += rv.w;
    }
    *(float4*)(C + (size_t)m * ldc + n0 + tx * 4) = r;
  }
}

// ---------------- global self-attention: nh=16, dh=64, P=256, causal ----------------
// one wave (64 thr) per (b, head, query)
__global__ void attn_global_kernel(const float* __restrict__ qkv, float* __restrict__ outp) {
  int bid = blockIdx.x;
  int qi = bid & (Pn - 1);
  int h  = (bid >> 8) & 15;
  int b  = bid >> 12;
  int lane = threadIdx.x;
  __shared__ float qsh[64];
  __shared__ float prob[Pn];
  const float* base = qkv + (size_t)b * Pn * 3 * Hdim;
  qsh[lane] = base[(size_t)qi * 3 * Hdim + h * 64 + lane];
  __syncthreads();
  float sv[4];
  float smax = -1e30f;
#pragma unroll
  for (int t = 0; t < 4; t++) {
    int kk = lane + t * 64;
    float s = -1e30f;
    if (kk <= qi) {
      const float* kr = base + (size_t)kk * 3 * Hdim + Hdim + h * 64;
      float d = 0.f;
#pragma unroll 16
      for (int j = 0; j < 64; j++) d = fmaf(qsh[j], kr[j], d);
      s = d * 0.125f;   // 1/sqrt(64)
    }
    sv[t] = s;
    smax = fmaxf(smax, s);
  }
#pragma unroll
  for (int off = 32; off; off >>= 1) smax = fmaxf(smax, __shfl_xor(smax, off));
  float lsum = 0.f;
#pragma unroll
  for (int t = 0; t < 4; t++) {
    float p = (sv[t] > -1e29f) ? __expf(sv[t] - smax) : 0.f;
    prob[lane + t * 64] = p;
    lsum += p;
  }
#pragma unroll
  for (int off = 32; off; off >>= 1) lsum += __shfl_xor(lsum, off);
  float rl = 1.0f / lsum;
  __syncthreads();
  const float* vb = base + 2 * Hdim + h * 64 + lane;
  float o = 0.f;
  for (int kk = 0; kk < Pn; ++kk) o = fmaf(prob[kk], vb[(size_t)kk * 3 * Hdim], o);
  outp[((size_t)(b * Pn + qi)) * Hdim + h * 64 + lane] = o * rl;
}

// ---------------- cross attention: nh=8, dh=128, Lq=4096, Lk=256, no mask ----------------
// one block (128 thr) per (b, head, query)
__global__ void attn_cross_kernel(const float* __restrict__ q, const float* __restrict__ k,
                                  const float* __restrict__ v, float* __restrict__ outp) {
  int bid = blockIdx.x;
  int qi = bid & (Slen - 1);
  int h  = (bid >> 12) & 7;
  int b  = bid >> 15;
  int lane = threadIdx.x;   // 0..127
  __shared__ float qsh[128];
  __shared__ float prob[Pn];
  __shared__ float wred[2][2];
  const float* qrow = q + ((size_t)(b * Slen + qi)) * Hdim + h * 128;
  qsh[lane] = qrow[lane];
  __syncthreads();
  const float* kb = k + (size_t)b * Pn * Hdim + h * 128;
  float sv[2];
  float smax = -1e30f;
#pragma unroll
  for (int t = 0; t < 2; t++) {
    const float* kr = kb + (size_t)(lane + t * 128) * Hdim;
    float d = 0.f;
#pragma unroll 16
    for (int j = 0; j < 128; j++) d = fmaf(qsh[j], kr[j], d);
    sv[t] = d * 0.088388347648318447f;  // 1/sqrt(128)
    smax = fmaxf(smax, sv[t]);
  }
#pragma unroll
  for (int off = 32; off; off >>= 1) smax = fmaxf(smax, __shfl_xor(smax, off));
  int wid = lane >> 6;
  if ((lane & 63) == 0) wred[0][wid] = smax;
  __syncthreads();
  smax = fmaxf(wred[0][0], wred[0][1]);
  float lsum = 0.f;
#pragma unroll
  for (int t = 0; t < 2; t++) {
    float p = __expf(sv[t] - smax);
    prob[lane + t * 128] = p;
    lsum += p;
  }
#pragma unroll
  for (int off = 32; off; off >>= 1) lsum += __shfl_xor(lsum, off);
  if ((lane & 63) == 0) wred[1][wid] = lsum;
  __syncthreads();
  float rl = 1.0f / (wred[1][0] + wred[1][1]);
  const float* vb = v + (size_t)b * Pn * Hdim + h * 128 + lane;
  float o = 0.f;
  for (int kk = 0; kk < Pn; ++kk) o = fmaf(prob[kk], vb[(size_t)kk * Hdim], o);
  outp[((size_t)(b * Slen + qi)) * Hdim + h * 128 + lane] = o * rl;
}

extern "C" void kernel_launch(void* const* d_in, const int* in_sizes, int n_in,
                              void* d_out, int out_size, void* d_ws, size_t ws_size,
                              hipStream_t stream) {
  const int*   byte_seq = (const int*)d_in[0];
  const int*   pbound   = (const int*)d_in[1];
  const float* emb      = (const float*)d_in[2];
  const float* g_ln1_g  = (const float*)d_in[3];
  const float* g_ln1_b  = (const float*)d_in[4];
  const float* g_wqkv   = (const float*)d_in[5];
  const float* g_bqkv   = (const float*)d_in[6];
  const float* g_wo     = (const float*)d_in[7];
  const float* g_bo     = (const float*)d_in[8];
  const float* g_ln2_g  = (const float*)d_in[9];
  const float* g_ln2_b  = (const float*)d_in[10];
  const float* g_w1     = (const float*)d_in[11];
  const float* g_b1     = (const float*)d_in[12];
  const float* g_w2     = (const float*)d_in[13];
  const float* g_b2     = (const float*)d_in[14];
  const float* fn_g     = (const float*)d_in[15];
  const float* fn_b     = (const float*)d_in[16];
  const float* ca_ln_g  = (const float*)d_in[17];
  const float* ca_ln_b  = (const float*)d_in[18];
  const float* ca_wqkv  = (const float*)d_in[19];
  const float* ca_bqkv  = (const float*)d_in[20];
  const float* ca_wo    = (const float*)d_in[21];
  const float* ca_bo    = (const float*)d_in[22];
  const float* head_w   = (const float*)d_in[23];
  const float* head_b   = (const float*)d_in[24];
  float* out = (float*)d_out;

  // workspace layout (floats)
  float* ws      = (float*)d_ws;
  float* x       = ws;                                   // B*S*H   = 8388608
  float* patches = x + (size_t)Bsz * Slen * Hdim;        // B*P*H   = 524288
  int*   pid     = (int*)(patches + (size_t)Bsz * Pn * Hdim);  // B*S ints
  float* nbuf    = (float*)(pid + Bsz * Slen);           // B*P*H
  float* qkv     = nbuf + (size_t)Bsz * Pn * Hdim;       // B*P*3H
  float* attn_o  = qkv + (size_t)Bsz * Pn * 3 * Hdim;    // B*P*H
  float* mid     = attn_o + (size_t)Bsz * Pn * Hdim;     // B*P*4H
  float* kbuf    = mid + (size_t)Bsz * Pn * 4 * Hdim;    // B*P*H
  float* vbuf    = kbuf + (size_t)Bsz * Pn * Hdim;       // B*P*H
  float* qn      = vbuf + (size_t)Bsz * Pn * Hdim;       // B*S*H
  float* qbuf    = qn + (size_t)Bsz * Slen * Hdim;       // B*S*H
  float* caout   = qn;  // reuse: qn dead once qbuf is computed

  // 1. byte embeddings
  embed_kernel<<<Bsz * Slen, 256, 0, stream>>>(byte_seq, emb, x);
  // 2. patch ids + mean pooling
  pid_kernel<<<(Bsz * Slen) / 256, 256, 0, stream>>>(pbound, pid);
  pool_kernel<<<Bsz * Pn, 256, 0, stream>>>(x, pid, patches);

  // 3. global transformer layers on patches [B*P, H]
  for (int l = 0; l < NLAY; ++l) {
    ln_kernel<<<Bsz * Pn, 256, 0, stream>>>(patches, g_ln1_g + l * Hdim, g_ln1_b + l * Hdim, nbuf);
    gemm_kernel<0><<<dim3(3 * Hdim / BN, Bsz * Pn / BM), 256, 0, stream>>>(
        nbuf, Hdim, g_wqkv + (size_t)l * Hdim * 3 * Hdim, 3 * Hdim,
        g_bqkv + l * 3 * Hdim, nullptr, qkv, 3 * Hdim, Hdim);
    attn_global_kernel<<<Bsz * 16 * Pn, 64, 0, stream>>>(qkv, attn_o);
    gemm_kernel<2><<<dim3(Hdim / BN, Bsz * Pn / BM), 256, 0, stream>>>(
        attn_o, Hdim, g_wo + (size_t)l * Hdim * Hdim, Hdim,
        g_bo + l * Hdim, patches, patches, Hdim, Hdim);
    ln_kernel<<<Bsz * Pn, 256, 0, stream>>>(patches, g_ln2_g + l * Hdim, g_ln2_b + l * Hdim, nbuf);
    gemm_kernel<1><<<dim3(4 * Hdim / BN, Bsz * Pn / BM), 256, 0, stream>>>(
        nbuf, Hdim, g_w1 + (size_t)l * Hdim * 4 * Hdim, 4 * Hdim,
        g_b1 + l * 4 * Hdim, nullptr, mid, 4 * Hdim, Hdim);
    gemm_kernel<2><<<dim3(Hdim / BN, Bsz * Pn / BM), 256, 0, stream>>>(
        mid, 4 * Hdim, g_w2 + (size_t)l * 4 * Hdim * Hdim, Hdim,
        g_b2 + l * Hdim, patches, patches, Hdim, 4 * Hdim);
  }

  // 4. final norm (in-place) then cross-attn LN of patches
  ln_kernel<<<Bsz * Pn, 256, 0, stream>>>(patches, fn_g, fn_b, patches);
  ln_kernel<<<Bsz * Pn, 256, 0, stream>>>(patches, ca_ln_g, ca_ln_b, nbuf);

  // 5. k, v projections from kvn (note ca_wqkv is [H, 3H] row-major: column offsets H, 2H)
  gemm_kernel<0><<<dim3(Hdim / BN, Bsz * Pn / BM), 256, 0, stream>>>(
      nbuf, Hdim, ca_wqkv + Hdim, 3 * Hdim, ca_bqkv + Hdim, nullptr, kbuf, Hdim, Hdim);
  gemm_kernel<0><<<dim3(Hdim / BN, Bsz * Pn / BM), 256, 0, stream>>>(
      nbuf, Hdim, ca_wqkv + 2 * Hdim, 3 * Hdim, ca_bqkv + 2 * Hdim, nullptr, vbuf, Hdim, Hdim);

  // 6. q projection from LN(x)
  ln_kernel<<<Bsz * Slen, 256, 0, stream>>>(x, ca_ln_g, ca_ln_b, qn);
  gemm_kernel<0><<<dim3(Hdim / BN, Bsz * Slen / BM), 256, 0, stream>>>(
      qn, Hdim, ca_wqkv, 3 * Hdim, ca_bqkv, nullptr, qbuf, Hdim, Hdim);

  // 7. cross attention (bytes attend to patches)
  attn_cross_kernel<<<Bsz * 8 * Slen, 128, 0, stream>>>(qbuf, kbuf, vbuf, caout);

  // 8. output projection + residual into x (in-place safe: each thread reads its own res elem)
  gemm_kernel<2><<<dim3(Hdim / BN, Bsz * Slen / BM), 256, 0, stream>>>(
      caout, Hdim, ca_wo, Hdim, ca_bo, x, x, Hdim, Hdim);

  // 9. head: logits = x @ head_w[1024,256] + head_b
  gemm_kernel<0><<<dim3(256 / BN, Bsz * Slen / BM), 256, 0, stream>>>(
      x, Hdim, head_w, 256, head_b, nullptr, out, 256, Hdim);
}

// Round 2
// 1463.707 us; speedup vs baseline: 3.2235x; 3.2235x over previous
//
#include <hip/hip_runtime.h>
#include <hip/hip_bf16.h>
#include <math.h>

#define Hdim 1024
#define Bsz  2
#define Slen 4096
#define Pn   256
#define NLAY 4

typedef __attribute__((ext_vector_type(8))) __bf16 bfrag;
typedef __attribute__((ext_vector_type(4))) float  f32x4;

__device__ __forceinline__ float gelu_exact(float x) {
  return 0.5f * x * (1.0f + erff(x * 0.70710678118654752f));
}
__device__ __forceinline__ short f2b(float x) {
  __hip_bfloat16 h = __float2bfloat16(x);
  return *reinterpret_cast<short*>(&h);
}
__device__ __forceinline__ void fma4(float4& a, float4 k, float q) {
  a.x = fmaf(k.x, q, a.x); a.y = fmaf(k.y, q, a.y);
  a.z = fmaf(k.z, q, a.z); a.w = fmaf(k.w, q, a.w);
}

// ---------------- embedding gather ----------------
__global__ void embed_kernel(const int* __restrict__ seq, const float* __restrict__ emb,
                             float* __restrict__ x) {
  int row = blockIdx.x;
  int tid = threadIdx.x;
  int tok = seq[row];
  float4 v = *(const float4*)(emb + (size_t)tok * Hdim + tid * 4);
  *(float4*)(x + (size_t)row * Hdim + tid * 4) = v;
}

// ---------------- patch ids ----------------
__global__ void pid_kernel(const int* __restrict__ bounds, int* __restrict__ pid) {
  int i = blockIdx.x * 256 + threadIdx.x;
  int b = i >> 12;
  int s = i & (Slen - 1);
  const int* bd = bounds + b * Pn;
  int lo = 0, hi = Pn;
  while (lo < hi) { int m = (lo + hi) >> 1; if (bd[m] <= s) lo = m + 1; else hi = m; }
  pid[i] = min(lo, Pn - 1);
}

// ---------------- patch mean pooling ----------------
__global__ void pool_kernel(const float* __restrict__ x, const int* __restrict__ pid,
                            float* __restrict__ patches) {
  int bp = blockIdx.x;
  int b = bp >> 8;
  int p = bp & (Pn - 1);
  const int* pv = pid + b * Slen;
  int lo = 0, hi = Slen;
  while (lo < hi) { int m = (lo + hi) >> 1; if (pv[m] < p) lo = m + 1; else hi = m; }
  int start = lo;
  lo = 0; hi = Slen;
  while (lo < hi) { int m = (lo + hi) >> 1; if (pv[m] < p + 1) lo = m + 1; else hi = m; }
  int end = lo;
  int tid = threadIdx.x;
  float4 acc = {0.f, 0.f, 0.f, 0.f};
  for (int s = start; s < end; ++s) {
    float4 xv = *(const float4*)(x + ((size_t)(b * Slen + s)) * Hdim + tid * 4);
    acc.x += xv.x; acc.y += xv.y; acc.z += xv.z; acc.w += xv.w;
  }
  float cnt = (float)(end - start);
  float r = 1.0f / fmaxf(cnt, 1.0f);
  float4 o = {acc.x * r, acc.y * r, acc.z * r, acc.w * r};
  *(float4*)(patches + (size_t)bp * Hdim + tid * 4) = o;
}

// ---------------- LayerNorm (OBF=1 -> bf16 out) ----------------
template<int OBF>
__global__ void ln_kernel(const float* __restrict__ in, const float* __restrict__ g,
                          const float* __restrict__ bvec, void* __restrict__ outv) {
  int row = blockIdx.x;
  int tid = threadIdx.x;
  const float* xr = in + (size_t)row * Hdim;
  float4 v = *(const float4*)(xr + tid * 4);
  float s  = v.x + v.y + v.z + v.w;
  float ss = v.x * v.x + v.y * v.y + v.z * v.z + v.w * v.w;
#pragma unroll
  for (int off = 32; off; off >>= 1) { s += __shfl_xor(s, off); ss += __shfl_xor(ss, off); }
  __shared__ float rs[4], rss[4];
  int wid = tid >> 6;
  if ((tid & 63) == 0) { rs[wid] = s; rss[wid] = ss; }
  __syncthreads();
  float tot  = rs[0] + rs[1] + rs[2] + rs[3];
  float tot2 = rss[0] + rss[1] + rss[2] + rss[3];
  float mu = tot * (1.0f / Hdim);
  float var = tot2 * (1.0f / Hdim) - mu * mu;
  float rstd = rsqrtf(var + 1e-6f);
  float4 gg = *(const float4*)(g + tid * 4);
  float4 bb = *(const float4*)(bvec + tid * 4);
  float4 r;
  r.x = (v.x - mu) * rstd * gg.x + bb.x;
  r.y = (v.y - mu) * rstd * gg.y + bb.y;
  r.z = (v.z - mu) * rstd * gg.z + bb.z;
  r.w = (v.w - mu) * rstd * gg.w + bb.w;
  if (OBF) {
    short4 o; o.x = f2b(r.x); o.y = f2b(r.y); o.z = f2b(r.z); o.w = f2b(r.w);
    *(short4*)((short*)outv + (size_t)row * Hdim + tid * 4) = o;
  } else {
    *(float4*)((float*)outv + (size_t)row * Hdim + tid * 4) = r;
  }
}

// ---------------- weight convert + transpose: f32 [K,N](ldin) -> bf16 [N,K] ----------------
__global__ void wconv_kernel(const float* __restrict__ in, short* __restrict__ out,
                             int ldin, int K, size_t in_lstride, size_t out_lstride) {
  int z = blockIdx.z;
  const float* src = in + (size_t)z * in_lstride;
  short* dst = out + (size_t)z * out_lstride;
  int n0 = blockIdx.x * 32, k0 = blockIdx.y * 32;
  int tx = threadIdx.x & 31, ty = threadIdx.x >> 5;
  __shared__ float t[32][33];
#pragma unroll
  for (int i = 0; i < 4; i++)
    t[ty + 8 * i][tx] = src[(size_t)(k0 + ty + 8 * i) * ldin + n0 + tx];
  __syncthreads();
#pragma unroll
  for (int i = 0; i < 4; i++)
    dst[(size_t)(n0 + ty + 8 * i) * K + k0 + tx] = f2b(t[tx][ty + 8 * i]);
}

// ---------------- K transpose for attention: picks head h, outputs [bh][d][kk] ----------------
__global__ void kt_kernel(const float* __restrict__ in, float* __restrict__ out,
                          int dh, int nh, int rowstride, int base) {
  int bh = blockIdx.z; int h = bh % nh; int b = bh / nh;
  int kk0 = blockIdx.x * 32, d0 = blockIdx.y * 32;
  int tx = threadIdx.x & 31, ty = threadIdx.x >> 5;
  __shared__ float t[32][33];
  const float* src = in + (size_t)b * Pn * rowstride + base + h * dh;
#pragma unroll
  for (int i = 0; i < 4; i++)
    t[ty + 8 * i][tx] = src[(size_t)(kk0 + ty + 8 * i) * rowstride + d0 + tx];
  __syncthreads();
  float* dst = out + (size_t)bh * dh * Pn;
#pragma unroll
  for (int i = 0; i < 4; i++)
    dst[(size_t)(d0 + ty + 8 * i) * Pn + kk0 + tx] = t[tx][ty + 8 * i];
}

// ---------------- bf16 MFMA GEMM: A[M,K]bf16 @ Bt[N,K]bf16 -> C[M,N] ----------------
// EPI: 0 bias, 1 bias+gelu, 2 bias+residual. OBF: 1 -> bf16 out, 0 -> f32 out.
template<int EPI, int OBF>
__launch_bounds__(256)
__global__ void gemm_bf16(const short* __restrict__ A, const short* __restrict__ Bt,
                          const float* __restrict__ bias, const float* __restrict__ res,
                          void* __restrict__ Cv, int ldc, int K) {
  __shared__ short As[128][40];   // row stride 80B: 16B-aligned, 2-way bank alias (free)
  __shared__ short Bs[128][40];
  int tid = threadIdx.x;
  int n0 = blockIdx.x * 128, m0 = blockIdx.y * 128;
  int lr = tid >> 2;             // 0..63
  int lc = (tid & 3) * 8;        // 0,8,16,24
  int wid = tid >> 6, lane = tid & 63;
  int wm = (wid & 1) * 64, wn = (wid >> 1) * 64;
  int quad = lane >> 4, l16 = lane & 15;
  f32x4 acc[4][4];
#pragma unroll
  for (int i = 0; i < 4; i++)
#pragma unroll
    for (int j = 0; j < 4; j++) acc[i][j] = (f32x4){0.f, 0.f, 0.f, 0.f};

  for (int k0 = 0; k0 < K; k0 += 32) {
    int4 av0 = *(const int4*)(A + (size_t)(m0 + lr) * K + k0 + lc);
    int4 av1 = *(const int4*)(A + (size_t)(m0 + lr + 64) * K + k0 + lc);
    int4 bv0 = *(const int4*)(Bt + (size_t)(n0 + lr) * K + k0 + lc);
    int4 bv1 = *(const int4*)(Bt + (size_t)(n0 + lr + 64) * K + k0 + lc);
    __syncthreads();
    *(int4*)&As[lr][lc] = av0;  *(int4*)&As[lr + 64][lc] = av1;
    *(int4*)&Bs[lr][lc] = bv0;  *(int4*)&Bs[lr + 64][lc] = bv1;
    __syncthreads();
    bfrag af[4], bfv[4];
#pragma unroll
    for (int mi = 0; mi < 4; mi++)
      af[mi] = *reinterpret_cast<const bfrag*>(&As[wm + mi * 16 + l16][quad * 8]);
#pragma unroll
    for (int ni = 0; ni < 4; ni++)
      bfv[ni] = *reinterpret_cast<const bfrag*>(&Bs[wn + ni * 16 + l16][quad * 8]);
#pragma unroll
    for (int mi = 0; mi < 4; mi++)
#pragma unroll
      for (int ni = 0; ni < 4; ni++)
        acc[mi][ni] = __builtin_amdgcn_mfma_f32_16x16x32_bf16(af[mi], bfv[ni], acc[mi][ni], 0, 0, 0);
  }

#pragma unroll
  for (int mi = 0; mi < 4; mi++)
#pragma unroll
    for (int ni = 0; ni < 4; ni++) {
      int c = n0 + wn + ni * 16 + l16;
      float bsv = bias[c];
#pragma unroll
      for (int reg = 0; reg < 4; reg++) {
        int r = m0 + wm + mi * 16 + quad * 4 + reg;
        float v = acc[mi][ni][reg] + bsv;
        if (EPI == 1) v = gelu_exact(v);
        if (EPI == 2) v += res[(size_t)r * ldc + c];
        if (OBF) ((short*)Cv)[(size_t)r * ldc + c] = f2b(v);
        else     ((float*)Cv)[(size_t)r * ldc + c] = v;
      }
    }
}

// ---------------- global self-attn v2: nh=16, dh=64, P=256, causal ----------------
// block = 4 waves, each wave handles 8 consecutive queries of one (b,h)
__launch_bounds__(256)
__global__ void attn_global2(const float* __restrict__ qkv, const float* __restrict__ Kt,
                             short* __restrict__ outp) {
  int qc = blockIdx.x & 7, bh = blockIdx.x >> 3;
  int h = bh & 15, b = bh >> 4;
  int wid = threadIdx.x >> 6, lane = threadIdx.x & 63;
  int q0 = qc * 32 + wid * 8;
  __shared__ float qshT[4][64][8];    // [wave][d][q]
  __shared__ float prob[4][8][256];
  const float* qbase = qkv + (size_t)b * Pn * 3072 + h * 64;
#pragma unroll
  for (int i = 0; i < 8; i++)
    qshT[wid][lane][i] = qbase[(size_t)(q0 + i) * 3072 + lane];
  __syncthreads();

  float4 sv[8];
#pragma unroll
  for (int i = 0; i < 8; i++) sv[i] = make_float4(0.f, 0.f, 0.f, 0.f);
  const float* ktb = Kt + (size_t)bh * 64 * Pn;
  for (int d = 0; d < 64; d++) {
    float4 kt = *(const float4*)(ktb + d * Pn + lane * 4);
    float qa[8];
    *(float4*)&qa[0] = *(const float4*)&qshT[wid][d][0];
    *(float4*)&qa[4] = *(const float4*)&qshT[wid][d][4];
#pragma unroll
    for (int i = 0; i < 8; i++) fma4(sv[i], kt, qa[i]);
  }

  float rl[8];
#pragma unroll
  for (int i = 0; i < 8; i++) {
    int qi = q0 + i;
    float sa[4] = {sv[i].x * 0.125f, sv[i].y * 0.125f, sv[i].z * 0.125f, sv[i].w * 0.125f};
    float mx = -1e30f;
#pragma unroll
    for (int t = 0; t < 4; t++) if (lane * 4 + t <= qi) mx = fmaxf(mx, sa[t]);
#pragma unroll
    for (int off = 32; off; off >>= 1) mx = fmaxf(mx, __shfl_xor(mx, off));
    float p[4], ls = 0.f;
#pragma unroll
    for (int t = 0; t < 4; t++) {
      p[t] = (lane * 4 + t <= qi) ? __expf(sa[t] - mx) : 0.f;
      ls += p[t];
    }
#pragma unroll
    for (int off = 32; off; off >>= 1) ls += __shfl_xor(ls, off);
    float4 p4 = {p[0], p[1], p[2], p[3]};
    *(float4*)&prob[wid][i][lane * 4] = p4;
    rl[i] = 1.0f / ls;
  }
  __syncthreads();

  const float* vb = qkv + (size_t)b * Pn * 3072 + 2048 + h * 64 + lane;
  float o[8] = {0.f, 0.f, 0.f, 0.f, 0.f, 0.f, 0.f, 0.f};
  int kend = q0 + 8;
  for (int kk = 0; kk < kend; kk++) {
    float v = vb[(size_t)kk * 3072];
#pragma unroll
    for (int i = 0; i < 8; i++) o[i] = fmaf(prob[wid][i][kk], v, o[i]);
  }
#pragma unroll
  for (int i = 0; i < 8; i++)
    outp[(size_t)(b * Pn + q0 + i) * Hdim + h * 64 + lane] = f2b(o[i] * rl[i]);
}

// ---------------- cross-attn v2: nh=8, dh=128, Lq=4096, Lk=256 ----------------
__launch_bounds__(256)
__global__ void attn_cross2(const float* __restrict__ q, const float* __restrict__ Kt,
                            const float* __restrict__ v, short* __restrict__ outp) {
  int qc = blockIdx.x & 127, bh = blockIdx.x >> 7;
  int h = bh & 7, b = bh >> 3;
  int wid = threadIdx.x >> 6, lane = threadIdx.x & 63;
  int q0 = qc * 32 + wid * 8;
  __shared__ float qshT[4][128][8];   // 16 KB
  __shared__ float prob[4][8][256];   // 32 KB
  const float* qb = q + (size_t)b * Slen * Hdim + h * 128;
#pragma unroll
  for (int i = 0; i < 16; i++) {
    int e = i * 64 + lane;
    int qi = e >> 7, d = e & 127;
    qshT[wid][d][qi] = qb[(size_t)(q0 + qi) * Hdim + d];
  }
  __syncthreads();

  float4 sv[8];
#pragma unroll
  for (int i = 0; i < 8; i++) sv[i] = make_float4(0.f, 0.f, 0.f, 0.f);
  const float* ktb = Kt + (size_t)bh * 128 * Pn;
  for (int d = 0; d < 128; d++) {
    float4 kt = *(const float4*)(ktb + d * Pn + lane * 4);
    float qa[8];
    *(float4*)&qa[0] = *(const float4*)&qshT[wid][d][0];
    *(float4*)&qa[4] = *(const float4*)&qshT[wid][d][4];
#pragma unroll
    for (int i = 0; i < 8; i++) fma4(sv[i], kt, qa[i]);
  }

  const float scale = 0.088388347648318447f;
  float rl[8];
#pragma unroll
  for (int i = 0; i < 8; i++) {
    float sa[4] = {sv[i].x * scale, sv[i].y * scale, sv[i].z * scale, sv[i].w * scale};
    float mx = fmaxf(fmaxf(sa[0], sa[1]), fmaxf(sa[2], sa[3]));
#pragma unroll
    for (int off = 32; off; off >>= 1) mx = fmaxf(mx, __shfl_xor(mx, off));
    float p[4], ls = 0.f;
#pragma unroll
    for (int t = 0; t < 4; t++) { p[t] = __expf(sa[t] - mx); ls += p[t]; }
#pragma unroll
    for (int off = 32; off; off >>= 1) ls += __shfl_xor(ls, off);
    float4 p4 = {p[0], p[1], p[2], p[3]};
    *(float4*)&prob[wid][i][lane * 4] = p4;
    rl[i] = 1.0f / ls;
  }
  __syncthreads();

  const float* vb = v + (size_t)b * Pn * Hdim + h * 128 + lane * 2;
  float2 o[8];
#pragma unroll
  for (int i = 0; i < 8; i++) o[i] = make_float2(0.f, 0.f);
  for (int kk = 0; kk < Pn; kk++) {
    float2 vv = *(const float2*)(vb + (size_t)kk * Hdim);
#pragma unroll
    for (int i = 0; i < 8; i++) {
      float p = prob[wid][i][kk];
      o[i].x = fmaf(p, vv.x, o[i].x);
      o[i].y = fmaf(p, vv.y, o[i].y);
    }
  }
#pragma unroll
  for (int i = 0; i < 8; i++) {
    short2 val;
    val.x = f2b(o[i].x * rl[i]);
    val.y = f2b(o[i].y * rl[i]);
    *(short2*)(outp + (size_t)(b * Slen + q0 + i) * Hdim + h * 128 + lane * 2) = val;
  }
}

extern "C" void kernel_launch(void* const* d_in, const int* in_sizes, int n_in,
                              void* d_out, int out_size, void* d_ws, size_t ws_size,
                              hipStream_t stream) {
  const int*   byte_seq = (const int*)d_in[0];
  const int*   pbound   = (const int*)d_in[1];
  const float* emb      = (const float*)d_in[2];
  const float* g_ln1_g  = (const float*)d_in[3];
  const float* g_ln1_b  = (const float*)d_in[4];
  const float* g_wqkv   = (const float*)d_in[5];
  const float* g_bqkv   = (const float*)d_in[6];
  const float* g_wo     = (const float*)d_in[7];
  const float* g_bo     = (const float*)d_in[8];
  const float* g_ln2_g  = (const float*)d_in[9];
  const float* g_ln2_b  = (const float*)d_in[10];
  const float* g_w1     = (const float*)d_in[11];
  const float* g_b1     = (const float*)d_in[12];
  const float* g_w2     = (const float*)d_in[13];
  const float* g_b2     = (const float*)d_in[14];
  const float* fn_g     = (const float*)d_in[15];
  const float* fn_b     = (const float*)d_in[16];
  const float* ca_ln_g  = (const float*)d_in[17];
  const float* ca_ln_b  = (const float*)d_in[18];
  const float* ca_wqkv  = (const float*)d_in[19];
  const float* ca_bqkv  = (const float*)d_in[20];
  const float* ca_wo    = (const float*)d_in[21];
  const float* ca_bo    = (const float*)d_in[22];
  const float* head_w   = (const float*)d_in[23];
  const float* head_b   = (const float*)d_in[24];
  float* out = (float*)d_out;

  // ---- workspace layout ----
  float* x       = (float*)d_ws;                 // 8388608 f32
  float* patches = x + 8388608;                  // 524288
  float* qkv     = patches + 524288;             // 1572864
  float* kbuf    = qkv + 1572864;                // 524288
  float* vbuf    = kbuf + 524288;                // 524288
  float* qbuf    = vbuf + 524288;                // 8388608
  float* Kt      = qbuf + 8388608;               // 524288 (shared: global layers, then cross)
  int*   pid     = (int*)(Kt + 524288);          // 8192 ints
  short* nbuf    = (short*)(pid + 8192);         // 524288 bf16
  short* attn_o  = nbuf + 524288;                // 524288
  short* mid     = attn_o + 524288;              // 2097152
  short* qn      = mid + 2097152;                // 8388608 (reused as caout after q-GEMM)
  short* xb      = qn + 8388608;                 // 8388608
  short* wqkv_t  = xb + 8388608;                 // 12582912
  short* wo_t    = wqkv_t + 12582912;            // 4194304
  short* w1_t    = wo_t + 4194304;               // 16777216
  short* w2_t    = w1_t + 16777216;              // 16777216
  short* caq_t   = w2_t + 16777216;              // 1048576
  short* cak_t   = caq_t + 1048576;              // 1048576
  short* cav_t   = cak_t + 1048576;              // 1048576
  short* cawo_t  = cav_t + 1048576;              // 1048576
  short* head_t  = cawo_t + 1048576;             // 262144
  short* caout   = qn;                           // alias

  // 1. byte embeddings, patch ids, pooling
  embed_kernel<<<Bsz * Slen, 256, 0, stream>>>(byte_seq, emb, x);
  pid_kernel<<<(Bsz * Slen) / 256, 256, 0, stream>>>(pbound, pid);
  pool_kernel<<<Bsz * Pn, 256, 0, stream>>>(x, pid, patches);

  // 2. weight convert + transpose to bf16 [N,K]
  wconv_kernel<<<dim3(96, 32, 4), 256, 0, stream>>>(g_wqkv, wqkv_t, 3072, 1024, 3145728, 3145728);
  wconv_kernel<<<dim3(32, 32, 4), 256, 0, stream>>>(g_wo, wo_t, 1024, 1024, 1048576, 1048576);
  wconv_kernel<<<dim3(128, 32, 4), 256, 0, stream>>>(g_w1, w1_t, 4096, 1024, 4194304, 4194304);
  wconv_kernel<<<dim3(32, 128, 4), 256, 0, stream>>>(g_w2, w2_t, 1024, 4096, 4194304, 4194304);
  wconv_kernel<<<dim3(32, 32, 3), 256, 0, stream>>>(ca_wqkv, caq_t, 3072, 1024, 1024, 1048576);
  wconv_kernel<<<dim3(32, 32, 1), 256, 0, stream>>>(ca_wo, cawo_t, 1024, 1024, 0, 0);
  wconv_kernel<<<dim3(8, 32, 1), 256, 0, stream>>>(head_w, head_t, 256, 1024, 0, 0);

  // 3. global transformer layers
  for (int l = 0; l < NLAY; ++l) {
    ln_kernel<1><<<Bsz * Pn, 256, 0, stream>>>(patches, g_ln1_g + l * Hdim, g_ln1_b + l * Hdim, nbuf);
    gemm_bf16<0, 0><<<dim3(24, 4), 256, 0, stream>>>(
        nbuf, wqkv_t + (size_t)l * 3145728, g_bqkv + l * 3072, nullptr, qkv, 3072, 1024);
    kt_kernel<<<dim3(8, 2, 32), 256, 0, stream>>>(qkv, Kt, 64, 16, 3072, 1024);
    attn_global2<<<256, 256, 0, stream>>>(qkv, Kt, attn_o);
    gemm_bf16<2, 0><<<dim3(8, 4), 256, 0, stream>>>(
        attn_o, wo_t + (size_t)l * 1048576, g_bo + l * Hdim, patches, patches, 1024, 1024);
    ln_kernel<1><<<Bsz * Pn, 256, 0, stream>>>(patches, g_ln2_g + l * Hdim, g_ln2_b + l * Hdim, nbuf);
    gemm_bf16<1, 1><<<dim3(32, 4), 256, 0, stream>>>(
        nbuf, w1_t + (size_t)l * 4194304, g_b1 + l * 4096, nullptr, mid, 4096, 1024);
    gemm_bf16<2, 0><<<dim3(8, 4), 256, 0, stream>>>(
        mid, w2_t + (size_t)l * 4194304, g_b2 + l * Hdim, patches, patches, 1024, 4096);
  }

  // 4. final norm (f32, in-place), then cross-attn LN of patches -> bf16
  ln_kernel<0><<<Bsz * Pn, 256, 0, stream>>>(patches, fn_g, fn_b, patches);
  ln_kernel<1><<<Bsz * Pn, 256, 0, stream>>>(patches, ca_ln_g, ca_ln_b, nbuf);

  // 5. k, v projections (f32 out for attention)
  gemm_bf16<0, 0><<<dim3(8, 4), 256, 0, stream>>>(
      nbuf, cak_t, ca_bqkv + 1024, nullptr, kbuf, 1024, 1024);
  gemm_bf16<0, 0><<<dim3(8, 4), 256, 0, stream>>>(
      nbuf, cav_t, ca_bqkv + 2048, nullptr, vbuf, 1024, 1024);

  // 6. q projection from LN(x)
  ln_kernel<1><<<Bsz * Slen, 256, 0, stream>>>(x, ca_ln_g, ca_ln_b, qn);
  gemm_bf16<0, 0><<<dim3(8, 64), 256, 0, stream>>>(
      qn, caq_t, ca_bqkv, nullptr, qbuf, 1024, 1024);

  // 7. cross attention (qn is dead now; caout aliases it)
  kt_kernel<<<dim3(8, 4, 16), 256, 0, stream>>>(kbuf, Kt, 128, 8, 1024, 0);
  attn_cross2<<<2048, 256, 0, stream>>>(qbuf, Kt, vbuf, caout);

  // 8. output projection + residual -> xb (bf16, feeds head)
  gemm_bf16<2, 1><<<dim3(8, 64), 256, 0, stream>>>(
      caout, cawo_t, ca_bo, x, xb, 1024, 1024);

  // 9. head
  gemm_bf16<0, 0><<<dim3(2, 64), 256, 0, stream>>>(
      xb, head_t, head_b, nullptr, out, 256, 1024);
}

// Round 3
// 1133.460 us; speedup vs baseline: 4.1628x; 1.2914x over previous
//
#include <hip/hip_runtime.h>
#include <hip/hip_bf16.h>
#include <math.h>

#define Hdim 1024
#define Bsz  2
#define Slen 4096
#define Pn   256
#define NLAY 4

typedef __attribute__((ext_vector_type(8))) __bf16 bfrag;
typedef __attribute__((ext_vector_type(4))) float  f32x4;

__device__ __forceinline__ float gelu_exact(float x) {
  return 0.5f * x * (1.0f + erff(x * 0.70710678118654752f));
}
__device__ __forceinline__ short f2b(float x) {
  __hip_bfloat16 h = __float2bfloat16(x);
  return *reinterpret_cast<short*>(&h);
}
__device__ __forceinline__ void fma4(float4& a, float4 k, float q) {
  a.x = fmaf(k.x, q, a.x); a.y = fmaf(k.y, q, a.y);
  a.z = fmaf(k.z, q, a.z); a.w = fmaf(k.w, q, a.w);
}

// ---------------- embedding gather ----------------
__global__ void embed_kernel(const int* __restrict__ seq, const float* __restrict__ emb,
                             float* __restrict__ x) {
  int row = blockIdx.x;
  int tid = threadIdx.x;
  int tok = seq[row];
  float4 v = *(const float4*)(emb + (size_t)tok * Hdim + tid * 4);
  *(float4*)(x + (size_t)row * Hdim + tid * 4) = v;
}

// ---------------- patch ids ----------------
__global__ void pid_kernel(const int* __restrict__ bounds, int* __restrict__ pid) {
  int i = blockIdx.x * 256 + threadIdx.x;
  int b = i >> 12;
  int s = i & (Slen - 1);
  const int* bd = bounds + b * Pn;
  int lo = 0, hi = Pn;
  while (lo < hi) { int m = (lo + hi) >> 1; if (bd[m] <= s) lo = m + 1; else hi = m; }
  pid[i] = min(lo, Pn - 1);
}

// ---------------- patch mean pooling ----------------
__global__ void pool_kernel(const float* __restrict__ x, const int* __restrict__ pid,
                            float* __restrict__ patches) {
  int bp = blockIdx.x;
  int b = bp >> 8;
  int p = bp & (Pn - 1);
  const int* pv = pid + b * Slen;
  int lo = 0, hi = Slen;
  while (lo < hi) { int m = (lo + hi) >> 1; if (pv[m] < p) lo = m + 1; else hi = m; }
  int start = lo;
  lo = 0; hi = Slen;
  while (lo < hi) { int m = (lo + hi) >> 1; if (pv[m] < p + 1) lo = m + 1; else hi = m; }
  int end = lo;
  int tid = threadIdx.x;
  float4 acc = {0.f, 0.f, 0.f, 0.f};
  for (int s = start; s < end; ++s) {
    float4 xv = *(const float4*)(x + ((size_t)(b * Slen + s)) * Hdim + tid * 4);
    acc.x += xv.x; acc.y += xv.y; acc.z += xv.z; acc.w += xv.w;
  }
  float cnt = (float)(end - start);
  float r = 1.0f / fmaxf(cnt, 1.0f);
  float4 o = {acc.x * r, acc.y * r, acc.z * r, acc.w * r};
  *(float4*)(patches + (size_t)bp * Hdim + tid * 4) = o;
}

// ---------------- LayerNorm (OBF=1 -> bf16 out) ----------------
template<int OBF>
__global__ void ln_kernel(const float* __restrict__ in, const float* __restrict__ g,
                          const float* __restrict__ bvec, void* __restrict__ outv) {
  int row = blockIdx.x;
  int tid = threadIdx.x;
  const float* xr = in + (size_t)row * Hdim;
  float4 v = *(const float4*)(xr + tid * 4);
  float s  = v.x + v.y + v.z + v.w;
  float ss = v.x * v.x + v.y * v.y + v.z * v.z + v.w * v.w;
#pragma unroll
  for (int off = 32; off; off >>= 1) { s += __shfl_xor(s, off); ss += __shfl_xor(ss, off); }
  __shared__ float rs[4], rss[4];
  int wid = tid >> 6;
  if ((tid & 63) == 0) { rs[wid] = s; rss[wid] = ss; }
  __syncthreads();
  float tot  = rs[0] + rs[1] + rs[2] + rs[3];
  float tot2 = rss[0] + rss[1] + rss[2] + rss[3];
  float mu = tot * (1.0f / Hdim);
  float var = tot2 * (1.0f / Hdim) - mu * mu;
  float rstd = rsqrtf(var + 1e-6f);
  float4 gg = *(const float4*)(g + tid * 4);
  float4 bb = *(const float4*)(bvec + tid * 4);
  float4 r;
  r.x = (v.x - mu) * rstd * gg.x + bb.x;
  r.y = (v.y - mu) * rstd * gg.y + bb.y;
  r.z = (v.z - mu) * rstd * gg.z + bb.z;
  r.w = (v.w - mu) * rstd * gg.w + bb.w;
  if (OBF) {
    short4 o; o.x = f2b(r.x); o.y = f2b(r.y); o.z = f2b(r.z); o.w = f2b(r.w);
    *(short4*)((short*)outv + (size_t)row * Hdim + tid * 4) = o;
  } else {
    *(float4*)((float*)outv + (size_t)row * Hdim + tid * 4) = r;
  }
}

// ---------------- weight convert + transpose: f32 [K,N](ldin) -> bf16 [N,K] ----------------
__global__ void wconv_kernel(const float* __restrict__ in, short* __restrict__ out,
                             int ldin, int K, size_t in_lstride, size_t out_lstride) {
  int z = blockIdx.z;
  const float* src = in + (size_t)z * in_lstride;
  short* dst = out + (size_t)z * out_lstride;
  int n0 = blockIdx.x * 32, k0 = blockIdx.y * 32;
  int tx = threadIdx.x & 31, ty = threadIdx.x >> 5;
  __shared__ float t[32][33];
#pragma unroll
  for (int i = 0; i < 4; i++)
    t[ty + 8 * i][tx] = src[(size_t)(k0 + ty + 8 * i) * ldin + n0 + tx];
  __syncthreads();
#pragma unroll
  for (int i = 0; i < 4; i++)
    dst[(size_t)(n0 + ty + 8 * i) * K + k0 + tx] = f2b(t[tx][ty + 8 * i]);
}

// ---------------- K transpose for global attention (f32): out [bh][d][kk] ----------------
__global__ void kt_kernel(const float* __restrict__ in, float* __restrict__ out,
                          int dh, int nh, int rowstride, int base) {
  int bh = blockIdx.z; int h = bh % nh; int b = bh / nh;
  int kk0 = blockIdx.x * 32, d0 = blockIdx.y * 32;
  int tx = threadIdx.x & 31, ty = threadIdx.x >> 5;
  __shared__ float t[32][33];
  const float* src = in + (size_t)b * Pn * rowstride + base + h * dh;
#pragma unroll
  for (int i = 0; i < 4; i++)
    t[ty + 8 * i][tx] = src[(size_t)(kk0 + ty + 8 * i) * rowstride + d0 + tx];
  __syncthreads();
  float* dst = out + (size_t)bh * dh * Pn;
#pragma unroll
  for (int i = 0; i < 4; i++)
    dst[(size_t)(d0 + ty + 8 * i) * Pn + kk0 + tx] = t[tx][ty + 8 * i];
}

// ---------------- V transpose for cross attention: f32 [b,key,h*128+d] -> bf16 [bh][d][key] ----------------
__global__ void vt_kernel(const float* __restrict__ in, short* __restrict__ out) {
  int bh = blockIdx.z; int h = bh & 7; int b = bh >> 3;
  int kk0 = blockIdx.x * 32, d0 = blockIdx.y * 32;
  int tx = threadIdx.x & 31, ty = threadIdx.x >> 5;
  __shared__ float t[32][33];
  const float* src = in + (size_t)b * Pn * Hdim + h * 128;
#pragma unroll
  for (int i = 0; i < 4; i++)
    t[ty + 8 * i][tx] = src[(size_t)(kk0 + ty + 8 * i) * Hdim + d0 + tx];
  __syncthreads();
  short* dst = out + (size_t)bh * 128 * 256;
#pragma unroll
  for (int i = 0; i < 4; i++)
    dst[(size_t)(d0 + ty + 8 * i) * 256 + kk0 + tx] = f2b(t[tx][ty + 8 * i]);
}

// ---------------- bf16 MFMA GEMM 128x128: A[M,K] @ Bt[N,K] -> C[M,N] ----------------
template<int EPI, int OBF>
__launch_bounds__(256)
__global__ void gemm_bf16(const short* __restrict__ A, const short* __restrict__ Bt,
                          const float* __restrict__ bias, const float* __restrict__ res,
                          void* __restrict__ Cv, int ldc, int K) {
  __shared__ short As[128][40];
  __shared__ short Bs[128][40];
  int tid = threadIdx.x;
  int n0 = blockIdx.x * 128, m0 = blockIdx.y * 128;
  int lr = tid >> 2;
  int lc = (tid & 3) * 8;
  int wid = tid >> 6, lane = tid & 63;
  int wm = (wid & 1) * 64, wn = (wid >> 1) * 64;
  int quad = lane >> 4, l16 = lane & 15;
  f32x4 acc[4][4];
#pragma unroll
  for (int i = 0; i < 4; i++)
#pragma unroll
    for (int j = 0; j < 4; j++) acc[i][j] = (f32x4){0.f, 0.f, 0.f, 0.f};

  for (int k0 = 0; k0 < K; k0 += 32) {
    int4 av0 = *(const int4*)(A + (size_t)(m0 + lr) * K + k0 + lc);
    int4 av1 = *(const int4*)(A + (size_t)(m0 + lr + 64) * K + k0 + lc);
    int4 bv0 = *(const int4*)(Bt + (size_t)(n0 + lr) * K + k0 + lc);
    int4 bv1 = *(const int4*)(Bt + (size_t)(n0 + lr + 64) * K + k0 + lc);
    __syncthreads();
    *(int4*)&As[lr][lc] = av0;  *(int4*)&As[lr + 64][lc] = av1;
    *(int4*)&Bs[lr][lc] = bv0;  *(int4*)&Bs[lr + 64][lc] = bv1;
    __syncthreads();
    bfrag af[4], bfv[4];
#pragma unroll
    for (int mi = 0; mi < 4; mi++)
      af[mi] = *reinterpret_cast<const bfrag*>(&As[wm + mi * 16 + l16][quad * 8]);
#pragma unroll
    for (int ni = 0; ni < 4; ni++)
      bfv[ni] = *reinterpret_cast<const bfrag*>(&Bs[wn + ni * 16 + l16][quad * 8]);
#pragma unroll
    for (int mi = 0; mi < 4; mi++)
#pragma unroll
      for (int ni = 0; ni < 4; ni++)
        acc[mi][ni] = __builtin_amdgcn_mfma_f32_16x16x32_bf16(af[mi], bfv[ni], acc[mi][ni], 0, 0, 0);
  }

#pragma unroll
  for (int mi = 0; mi < 4; mi++)
#pragma unroll
    for (int ni = 0; ni < 4; ni++) {
      int c = n0 + wn + ni * 16 + l16;
      float bsv = bias[c];
#pragma unroll
      for (int reg = 0; reg < 4; reg++) {
        int r = m0 + wm + mi * 16 + quad * 4 + reg;
        float v = acc[mi][ni][reg] + bsv;
        if (EPI == 1) v = gelu_exact(v);
        if (EPI == 2) v += res[(size_t)r * ldc + c];
        if (OBF) ((short*)Cv)[(size_t)r * ldc + c] = f2b(v);
        else     ((float*)Cv)[(size_t)r * ldc + c] = v;
      }
    }
}

// ---------------- bf16 MFMA GEMM 64x64 (for small-M shapes: 4x the blocks) ----------------
template<int EPI, int OBF>
__launch_bounds__(256)
__global__ void gemm_bf16_64(const short* __restrict__ A, const short* __restrict__ Bt,
                             const float* __restrict__ bias, const float* __restrict__ res,
                             void* __restrict__ Cv, int ldc, int K) {
  __shared__ short As[64][40];
  __shared__ short Bs[64][40];
  int tid = threadIdx.x;
  int n0 = blockIdx.x * 64, m0 = blockIdx.y * 64;
  int lr = tid >> 2;
  int lc = (tid & 3) * 8;
  int wid = tid >> 6, lane = tid & 63;
  int wm = (wid & 1) * 32, wn = (wid >> 1) * 32;
  int quad = lane >> 4, l16 = lane & 15;
  f32x4 acc[2][2];
#pragma unroll
  for (int i = 0; i < 2; i++)
#pragma unroll
    for (int j = 0; j < 2; j++) acc[i][j] = (f32x4){0.f, 0.f, 0.f, 0.f};

  for (int k0 = 0; k0 < K; k0 += 32) {
    int4 av = *(const int4*)(A + (size_t)(m0 + lr) * K + k0 + lc);
    int4 bv = *(const int4*)(Bt + (size_t)(n0 + lr) * K + k0 + lc);
    __syncthreads();
    *(int4*)&As[lr][lc] = av;
    *(int4*)&Bs[lr][lc] = bv;
    __syncthreads();
    bfrag af[2], bfv[2];
#pragma unroll
    for (int mi = 0; mi < 2; mi++)
      af[mi] = *reinterpret_cast<const bfrag*>(&As[wm + mi * 16 + l16][quad * 8]);
#pragma unroll
    for (int ni = 0; ni < 2; ni++)
      bfv[ni] = *reinterpret_cast<const bfrag*>(&Bs[wn + ni * 16 + l16][quad * 8]);
#pragma unroll
    for (int mi = 0; mi < 2; mi++)
#pragma unroll
      for (int ni = 0; ni < 2; ni++)
        acc[mi][ni] = __builtin_amdgcn_mfma_f32_16x16x32_bf16(af[mi], bfv[ni], acc[mi][ni], 0, 0, 0);
  }

#pragma unroll
  for (int mi = 0; mi < 2; mi++)
#pragma unroll
    for (int ni = 0; ni < 2; ni++) {
      int c = n0 + wn + ni * 16 + l16;
      float bsv = bias[c];
#pragma unroll
      for (int reg = 0; reg < 4; reg++) {
        int r = m0 + wm + mi * 16 + quad * 4 + reg;
        float v = acc[mi][ni][reg] + bsv;
        if (EPI == 1) v = gelu_exact(v);
        if (EPI == 2) v += res[(size_t)r * ldc + c];
        if (OBF) ((short*)Cv)[(size_t)r * ldc + c] = f2b(v);
        else     ((float*)Cv)[(size_t)r * ldc + c] = v;
      }
    }
}

// ---------------- global self-attn: nh=16, dh=64, P=256, causal (f32 VALU) ----------------
__launch_bounds__(256)
__global__ void attn_global2(const float* __restrict__ qkv, const float* __restrict__ Kt,
                             short* __restrict__ outp) {
  int qc = blockIdx.x & 7, bh = blockIdx.x >> 3;
  int h = bh & 15, b = bh >> 4;
  int wid = threadIdx.x >> 6, lane = threadIdx.x & 63;
  int q0 = qc * 32 + wid * 8;
  __shared__ float qshT[4][64][8];
  __shared__ float prob[4][8][256];
  const float* qbase = qkv + (size_t)b * Pn * 3072 + h * 64;
#pragma unroll
  for (int i = 0; i < 8; i++)
    qshT[wid][lane][i] = qbase[(size_t)(q0 + i) * 3072 + lane];
  __syncthreads();

  float4 sv[8];
#pragma unroll
  for (int i = 0; i < 8; i++) sv[i] = make_float4(0.f, 0.f, 0.f, 0.f);
  const float* ktb = Kt + (size_t)bh * 64 * Pn;
  for (int d = 0; d < 64; d++) {
    float4 kt = *(const float4*)(ktb + d * Pn + lane * 4);
    float qa[8];
    *(float4*)&qa[0] = *(const float4*)&qshT[wid][d][0];
    *(float4*)&qa[4] = *(const float4*)&qshT[wid][d][4];
#pragma unroll
    for (int i = 0; i < 8; i++) fma4(sv[i], kt, qa[i]);
  }

  float rl[8];
#pragma unroll
  for (int i = 0; i < 8; i++) {
    int qi = q0 + i;
    float sa[4] = {sv[i].x * 0.125f, sv[i].y * 0.125f, sv[i].z * 0.125f, sv[i].w * 0.125f};
    float mx = -1e30f;
#pragma unroll
    for (int t = 0; t < 4; t++) if (lane * 4 + t <= qi) mx = fmaxf(mx, sa[t]);
#pragma unroll
    for (int off = 32; off; off >>= 1) mx = fmaxf(mx, __shfl_xor(mx, off));
    float p[4], ls = 0.f;
#pragma unroll
    for (int t = 0; t < 4; t++) {
      p[t] = (lane * 4 + t <= qi) ? __expf(sa[t] - mx) : 0.f;
      ls += p[t];
    }
#pragma unroll
    for (int off = 32; off; off >>= 1) ls += __shfl_xor(ls, off);
    float4 p4 = {p[0], p[1], p[2], p[3]};
    *(float4*)&prob[wid][i][lane * 4] = p4;
    rl[i] = 1.0f / ls;
  }
  __syncthreads();

  const float* vb = qkv + (size_t)b * Pn * 3072 + 2048 + h * 64 + lane;
  float o[8] = {0.f, 0.f, 0.f, 0.f, 0.f, 0.f, 0.f, 0.f};
  int kend = q0 + 8;
  for (int kk = 0; kk < kend; kk++) {
    float v = vb[(size_t)kk * 3072];
#pragma unroll
    for (int i = 0; i < 8; i++) o[i] = fmaf(prob[wid][i][kk], v, o[i]);
  }
#pragma unroll
  for (int i = 0; i < 8; i++)
    outp[(size_t)(b * Pn + q0 + i) * Hdim + h * 64 + lane] = f2b(o[i] * rl[i]);
}

// ---------------- cross-attn v3: MFMA flash. nh=8, dh=128, Lq=4096, Lk=256 ----------------
// grid: (Slen/64, B*8). block = 4 waves; each wave owns 16 q-rows.
// Q [B,S,H] bf16, K [B,Pn,H] bf16, Vt [bh][128][256] bf16.
__launch_bounds__(256)
__global__ void attn_cross3(const short* __restrict__ q, const short* __restrict__ k,
                            const short* __restrict__ vt, short* __restrict__ outp) {
  int bh = blockIdx.y; int h = bh & 7; int b = bh >> 3;
  int wid = threadIdx.x >> 6, lane = threadIdx.x & 63;
  int quad = lane >> 4, l16 = lane & 15;
  int q0 = blockIdx.x * 64 + wid * 16;
  __shared__ short Pl[4][16][264];   // 264 = 256 + 8 pad (16B) -> conflict-free b128 reads

  const short* qbase = q + ((size_t)(b * Slen + q0 + l16)) * Hdim + h * 128 + quad * 8;
  const short* kbase = k + ((size_t)(b * Pn + l16)) * Hdim + h * 128 + quad * 8;

  // S = Q K^T : M=16 (per wave), N=256, Kd=128
  f32x4 sacc[16];
#pragma unroll
  for (int n = 0; n < 16; n++) sacc[n] = (f32x4){0.f, 0.f, 0.f, 0.f};
#pragma unroll
  for (int ks = 0; ks < 4; ks++) {
    bfrag aq = *(const bfrag*)(qbase + ks * 32);
#pragma unroll
    for (int n = 0; n < 16; n++) {
      bfrag kf = *(const bfrag*)(kbase + (size_t)(n * 16) * Hdim + ks * 32);
      sacc[n] = __builtin_amdgcn_mfma_f32_16x16x32_bf16(aq, kf, sacc[n], 0, 0, 0);
    }
  }

  // softmax over 256 cols; rows = quad*4 + reg; cols of frag n = n*16 + l16
  const float scale = 0.088388347648318447f;
  float mx[4] = {-1e30f, -1e30f, -1e30f, -1e30f};
#pragma unroll
  for (int n = 0; n < 16; n++)
#pragma unroll
    for (int r = 0; r < 4; r++) mx[r] = fmaxf(mx[r], sacc[n][r]);
#pragma unroll
  for (int off = 1; off < 16; off <<= 1)
#pragma unroll
    for (int r = 0; r < 4; r++) mx[r] = fmaxf(mx[r], __shfl_xor(mx[r], off));
  float ls[4] = {0.f, 0.f, 0.f, 0.f};
#pragma unroll
  for (int n = 0; n < 16; n++)
#pragma unroll
    for (int r = 0; r < 4; r++) {
      float p = __expf((sacc[n][r] - mx[r]) * scale);
      Pl[wid][quad * 4 + r][n * 16 + l16] = f2b(p);
      ls[r] += p;
    }
#pragma unroll
  for (int off = 1; off < 16; off <<= 1)
#pragma unroll
    for (int r = 0; r < 4; r++) ls[r] += __shfl_xor(ls[r], off);
  float rl[4];
#pragma unroll
  for (int r = 0; r < 4; r++) rl[r] = 1.0f / ls[r];
  __syncthreads();

  // O = P V : M=16, N=128, Kk=256. A = Pl (LDS), Bt = Vt (global)
  f32x4 oacc[8];
#pragma unroll
  for (int n = 0; n < 8; n++) oacc[n] = (f32x4){0.f, 0.f, 0.f, 0.f};
  const short* vtb = vt + (size_t)bh * 128 * 256;
#pragma unroll
  for (int ks = 0; ks < 8; ks++) {
    bfrag pa = *reinterpret_cast<const bfrag*>(&Pl[wid][l16][ks * 32 + quad * 8]);
#pragma unroll
    for (int n = 0; n < 8; n++) {
      bfrag vf = *(const bfrag*)(vtb + (size_t)(n * 16 + l16) * 256 + ks * 32 + quad * 8);
      oacc[n] = __builtin_amdgcn_mfma_f32_16x16x32_bf16(pa, vf, oacc[n], 0, 0, 0);
    }
  }

#pragma unroll
  for (int n = 0; n < 8; n++)
#pragma unroll
    for (int r = 0; r < 4; r++) {
      int row = q0 + quad * 4 + r;
      outp[(size_t)(b * Slen + row) * Hdim + h * 128 + n * 16 + l16] = f2b(oacc[n][r] * rl[r]);
    }
}

extern "C" void kernel_launch(void* const* d_in, const int* in_sizes, int n_in,
                              void* d_out, int out_size, void* d_ws, size_t ws_size,
                              hipStream_t stream) {
  const int*   byte_seq = (const int*)d_in[0];
  const int*   pbound   = (const int*)d_in[1];
  const float* emb      = (const float*)d_in[2];
  const float* g_ln1_g  = (const float*)d_in[3];
  const float* g_ln1_b  = (const float*)d_in[4];
  const float* g_wqkv   = (const float*)d_in[5];
  const float* g_bqkv   = (const float*)d_in[6];
  const float* g_wo     = (const float*)d_in[7];
  const float* g_bo     = (const float*)d_in[8];
  const float* g_ln2_g  = (const float*)d_in[9];
  const float* g_ln2_b  = (const float*)d_in[10];
  const float* g_w1     = (const float*)d_in[11];
  const float* g_b1     = (const float*)d_in[12];
  const float* g_w2     = (const float*)d_in[13];
  const float* g_b2     = (const float*)d_in[14];
  const float* fn_g     = (const float*)d_in[15];
  const float* fn_b     = (const float*)d_in[16];
  const float* ca_ln_g  = (const float*)d_in[17];
  const float* ca_ln_b  = (const float*)d_in[18];
  const float* ca_wqkv  = (const float*)d_in[19];
  const float* ca_bqkv  = (const float*)d_in[20];
  const float* ca_wo    = (const float*)d_in[21];
  const float* ca_bo    = (const float*)d_in[22];
  const float* head_w   = (const float*)d_in[23];
  const float* head_b   = (const float*)d_in[24];
  float* out = (float*)d_out;

  // ---- workspace layout ----
  float* x       = (float*)d_ws;                 // 8388608 f32
  float* patches = x + 8388608;                  // 524288
  float* qkv     = patches + 524288;             // 1572864
  float* vbuf    = qkv + 1572864;                // 524288
  float* Kt      = vbuf + 524288;                // 524288 (global-attn K^T, f32)
  int*   pid     = (int*)(Kt + 524288);          // 8192 ints
  short* nbuf    = (short*)(pid + 8192);         // 524288 bf16
  short* attn_o  = nbuf + 524288;                // 524288
  short* mid     = attn_o + 524288;              // 2097152
  short* qn      = mid + 2097152;                // 8388608 (LN(x) bf16; reused as caout)
  short* qb      = qn + 8388608;                 // 8388608 (q bf16)
  short* xb      = qb + 8388608;                 // 8388608
  short* kb      = xb + 8388608;                 // 524288 (cross K bf16)
  short* vt      = kb + 524288;                  // 524288 (cross V^T bf16)
  short* wqkv_t  = vt + 524288;                  // 12582912
  short* wo_t    = wqkv_t + 12582912;            // 4194304
  short* w1_t    = wo_t + 4194304;               // 16777216
  short* w2_t    = w1_t + 16777216;              // 16777216
  short* caq_t   = w2_t + 16777216;              // 1048576
  short* cak_t   = caq_t + 1048576;              // 1048576
  short* cav_t   = cak_t + 1048576;              // 1048576
  short* cawo_t  = cav_t + 1048576;              // 1048576
  short* head_t  = cawo_t + 1048576;             // 262144
  short* caout   = qn;                           // alias (qn dead after q-proj)

  // 1. byte embeddings, patch ids, pooling
  embed_kernel<<<Bsz * Slen, 256, 0, stream>>>(byte_seq, emb, x);
  pid_kernel<<<(Bsz * Slen) / 256, 256, 0, stream>>>(pbound, pid);
  pool_kernel<<<Bsz * Pn, 256, 0, stream>>>(x, pid, patches);

  // 2. weight convert + transpose to bf16 [N,K]
  wconv_kernel<<<dim3(96, 32, 4), 256, 0, stream>>>(g_wqkv, wqkv_t, 3072, 1024, 3145728, 3145728);
  wconv_kernel<<<dim3(32, 32, 4), 256, 0, stream>>>(g_wo, wo_t, 1024, 1024, 1048576, 1048576);
  wconv_kernel<<<dim3(128, 32, 4), 256, 0, stream>>>(g_w1, w1_t, 4096, 1024, 4194304, 4194304);
  wconv_kernel<<<dim3(32, 128, 4), 256, 0, stream>>>(g_w2, w2_t, 1024, 4096, 4194304, 4194304);
  wconv_kernel<<<dim3(32, 32, 3), 256, 0, stream>>>(ca_wqkv, caq_t, 3072, 1024, 1024, 1048576);
  wconv_kernel<<<dim3(32, 32, 1), 256, 0, stream>>>(ca_wo, cawo_t, 1024, 1024, 0, 0);
  wconv_kernel<<<dim3(8, 32, 1), 256, 0, stream>>>(head_w, head_t, 256, 1024, 0, 0);

  // 3. global transformer layers (M=512 -> 64x64-tile GEMMs)
  for (int l = 0; l < NLAY; ++l) {
    ln_kernel<1><<<Bsz * Pn, 256, 0, stream>>>(patches, g_ln1_g + l * Hdim, g_ln1_b + l * Hdim, nbuf);
    gemm_bf16_64<0, 0><<<dim3(48, 8), 256, 0, stream>>>(
        nbuf, wqkv_t + (size_t)l * 3145728, g_bqkv + l * 3072, nullptr, qkv, 3072, 1024);
    kt_kernel<<<dim3(8, 2, 32), 256, 0, stream>>>(qkv, Kt, 64, 16, 3072, 1024);
    attn_global2<<<256, 256, 0, stream>>>(qkv, Kt, attn_o);
    gemm_bf16_64<2, 0><<<dim3(16, 8), 256, 0, stream>>>(
        attn_o, wo_t + (size_t)l * 1048576, g_bo + l * Hdim, patches, patches, 1024, 1024);
    ln_kernel<1><<<Bsz * Pn, 256, 0, stream>>>(patches, g_ln2_g + l * Hdim, g_ln2_b + l * Hdim, nbuf);
    gemm_bf16_64<1, 1><<<dim3(64, 8), 256, 0, stream>>>(
        nbuf, w1_t + (size_t)l * 4194304, g_b1 + l * 4096, nullptr, mid, 4096, 1024);
    gemm_bf16_64<2, 0><<<dim3(16, 8), 256, 0, stream>>>(
        mid, w2_t + (size_t)l * 4194304, g_b2 + l * Hdim, patches, patches, 1024, 4096);
  }

  // 4. final norm (f32, in-place), then cross-attn LN of patches -> bf16
  ln_kernel<0><<<Bsz * Pn, 256, 0, stream>>>(patches, fn_g, fn_b, patches);
  ln_kernel<1><<<Bsz * Pn, 256, 0, stream>>>(patches, ca_ln_g, ca_ln_b, nbuf);

  // 5. k (bf16 out), v (f32 out -> transposed bf16)
  gemm_bf16_64<0, 1><<<dim3(16, 8), 256, 0, stream>>>(
      nbuf, cak_t, ca_bqkv + 1024, nullptr, kb, 1024, 1024);
  gemm_bf16_64<0, 0><<<dim3(16, 8), 256, 0, stream>>>(
      nbuf, cav_t, ca_bqkv + 2048, nullptr, vbuf, 1024, 1024);
  vt_kernel<<<dim3(8, 4, 16), 256, 0, stream>>>(vbuf, vt);

  // 6. q projection from LN(x) -> bf16
  ln_kernel<1><<<Bsz * Slen, 256, 0, stream>>>(x, ca_ln_g, ca_ln_b, qn);
  gemm_bf16<0, 1><<<dim3(8, 64), 256, 0, stream>>>(
      qn, caq_t, ca_bqkv, nullptr, qb, 1024, 1024);

  // 7. MFMA cross attention (qn dead; caout aliases it)
  attn_cross3<<<dim3(64, 16), 256, 0, stream>>>(qb, kb, vt, caout);

  // 8. output projection + residual -> xb (bf16, feeds head)
  gemm_bf16<2, 1><<<dim3(8, 64), 256, 0, stream>>>(
      caout, cawo_t, ca_bo, x, xb, 1024, 1024);

  // 9. head (N=256 -> 64-tile for grid size)
  gemm_bf16_64<0, 0><<<dim3(4, 128), 256, 0, stream>>>(
      xb, head_t, head_b, nullptr, out, 256, 1024);
}

// Round 4
// 855.732 us; speedup vs baseline: 5.5138x; 1.3246x over previous
//
#include <hip/hip_runtime.h>
#include <hip/hip_bf16.h>
#include <math.h>

#define Hdim 1024
#define Bsz  2
#define Slen 4096
#define Pn   256
#define NLAY 4

typedef __attribute__((ext_vector_type(8))) __bf16 bfrag;
typedef __attribute__((ext_vector_type(4))) float  f32x4;

__device__ __forceinline__ float gelu_exact(float x) {
  return 0.5f * x * (1.0f + erff(x * 0.70710678118654752f));
}
__device__ __forceinline__ short f2b(float x) {
  __hip_bfloat16 h = __float2bfloat16(x);
  return *reinterpret_cast<short*>(&h);
}

// ---------------- embedding gather ----------------
__global__ void embed_kernel(const int* __restrict__ seq, const float* __restrict__ emb,
                             float* __restrict__ x) {
  int row = blockIdx.x;
  int tid = threadIdx.x;
  int tok = seq[row];
  float4 v = *(const float4*)(emb + (size_t)tok * Hdim + tid * 4);
  *(float4*)(x + (size_t)row * Hdim + tid * 4) = v;
}

// ---------------- patch ids ----------------
__global__ void pid_kernel(const int* __restrict__ bounds, int* __restrict__ pid) {
  int i = blockIdx.x * 256 + threadIdx.x;
  int b = i >> 12;
  int s = i & (Slen - 1);
  const int* bd = bounds + b * Pn;
  int lo = 0, hi = Pn;
  while (lo < hi) { int m = (lo + hi) >> 1; if (bd[m] <= s) lo = m + 1; else hi = m; }
  pid[i] = min(lo, Pn - 1);
}

// ---------------- patch mean pooling ----------------
__global__ void pool_kernel(const float* __restrict__ x, const int* __restrict__ pid,
                            float* __restrict__ patches) {
  int bp = blockIdx.x;
  int b = bp >> 8;
  int p = bp & (Pn - 1);
  const int* pv = pid + b * Slen;
  int lo = 0, hi = Slen;
  while (lo < hi) { int m = (lo + hi) >> 1; if (pv[m] < p) lo = m + 1; else hi = m; }
  int start = lo;
  lo = 0; hi = Slen;
  while (lo < hi) { int m = (lo + hi) >> 1; if (pv[m] < p + 1) lo = m + 1; else hi = m; }
  int end = lo;
  int tid = threadIdx.x;
  float4 acc = {0.f, 0.f, 0.f, 0.f};
  for (int s = start; s < end; ++s) {
    float4 xv = *(const float4*)(x + ((size_t)(b * Slen + s)) * Hdim + tid * 4);
    acc.x += xv.x; acc.y += xv.y; acc.z += xv.z; acc.w += xv.w;
  }
  float cnt = (float)(end - start);
  float r = 1.0f / fmaxf(cnt, 1.0f);
  float4 o = {acc.x * r, acc.y * r, acc.z * r, acc.w * r};
  *(float4*)(patches + (size_t)bp * Hdim + tid * 4) = o;
}

// ---------------- LayerNorm (OBF=1 -> bf16 out) ----------------
template<int OBF>
__global__ void ln_kernel(const float* __restrict__ in, const float* __restrict__ g,
                          const float* __restrict__ bvec, void* __restrict__ outv) {
  int row = blockIdx.x;
  int tid = threadIdx.x;
  const float* xr = in + (size_t)row * Hdim;
  float4 v = *(const float4*)(xr + tid * 4);
  float s  = v.x + v.y + v.z + v.w;
  float ss = v.x * v.x + v.y * v.y + v.z * v.z + v.w * v.w;
#pragma unroll
  for (int off = 32; off; off >>= 1) { s += __shfl_xor(s, off); ss += __shfl_xor(ss, off); }
  __shared__ float rs[4], rss[4];
  int wid = tid >> 6;
  if ((tid & 63) == 0) { rs[wid] = s; rss[wid] = ss; }
  __syncthreads();
  float tot  = rs[0] + rs[1] + rs[2] + rs[3];
  float tot2 = rss[0] + rss[1] + rss[2] + rss[3];
  float mu = tot * (1.0f / Hdim);
  float var = tot2 * (1.0f / Hdim) - mu * mu;
  float rstd = rsqrtf(var + 1e-6f);
  float4 gg = *(const float4*)(g + tid * 4);
  float4 bb = *(const float4*)(bvec + tid * 4);
  float4 r;
  r.x = (v.x - mu) * rstd * gg.x + bb.x;
  r.y = (v.y - mu) * rstd * gg.y + bb.y;
  r.z = (v.z - mu) * rstd * gg.z + bb.z;
  r.w = (v.w - mu) * rstd * gg.w + bb.w;
  if (OBF) {
    short4 o; o.x = f2b(r.x); o.y = f2b(r.y); o.z = f2b(r.z); o.w = f2b(r.w);
    *(short4*)((short*)outv + (size_t)row * Hdim + tid * 4) = o;
  } else {
    *(float4*)((float*)outv + (size_t)row * Hdim + tid * 4) = r;
  }
}

// ---------------- weight convert + transpose: f32 [K,N](ldin) -> bf16 [N,K] ----------------
__global__ void wconv_kernel(const float* __restrict__ in, short* __restrict__ out,
                             int ldin, int K, size_t in_lstride, size_t out_lstride) {
  int z = blockIdx.z;
  const float* src = in + (size_t)z * in_lstride;
  short* dst = out + (size_t)z * out_lstride;
  int n0 = blockIdx.x * 32, k0 = blockIdx.y * 32;
  int tx = threadIdx.x & 31, ty = threadIdx.x >> 5;
  __shared__ float t[32][33];
#pragma unroll
  for (int i = 0; i < 4; i++)
    t[ty + 8 * i][tx] = src[(size_t)(k0 + ty + 8 * i) * ldin + n0 + tx];
  __syncthreads();
#pragma unroll
  for (int i = 0; i < 4; i++)
    dst[(size_t)(n0 + ty + 8 * i) * K + k0 + tx] = f2b(t[tx][ty + 8 * i]);
}

// ---------------- V transpose for cross attention: f32 [b,key,h*128+d] -> bf16 [bh][d][key] ----------------
__global__ void vt_kernel(const float* __restrict__ in, short* __restrict__ out) {
  int bh = blockIdx.z; int h = bh & 7; int b = bh >> 3;
  int kk0 = blockIdx.x * 32, d0 = blockIdx.y * 32;
  int tx = threadIdx.x & 31, ty = threadIdx.x >> 5;
  __shared__ float t[32][33];
  const float* src = in + (size_t)b * Pn * Hdim + h * 128;
#pragma unroll
  for (int i = 0; i < 4; i++)
    t[ty + 8 * i][tx] = src[(size_t)(kk0 + ty + 8 * i) * Hdim + d0 + tx];
  __syncthreads();
  short* dst = out + (size_t)bh * 128 * 256;
#pragma unroll
  for (int i = 0; i < 4; i++)
    dst[(size_t)(d0 + ty + 8 * i) * 256 + kk0 + tx] = f2b(t[tx][ty + 8 * i]);
}

// ---------------- V^T for global attn: bf16 qkv [b,key,3072] (v at 2048+h*64) -> [bh][d=64][key=256] ----------------
__global__ void vtg_kernel(const short* __restrict__ qkvb, short* __restrict__ out) {
  int bh = blockIdx.z; int h = bh & 15; int b = bh >> 4;
  int kk0 = blockIdx.x * 32, d0 = blockIdx.y * 32;
  int tx = threadIdx.x & 31, ty = threadIdx.x >> 5;
  __shared__ short t[32][33];
  const short* src = qkvb + (size_t)b * Pn * 3072 + 2048 + h * 64;
#pragma unroll
  for (int i = 0; i < 4; i++)
    t[ty + 8 * i][tx] = src[(size_t)(kk0 + ty + 8 * i) * 3072 + d0 + tx];
  __syncthreads();
  short* dst = out + (size_t)bh * 64 * 256;
#pragma unroll
  for (int i = 0; i < 4; i++)
    dst[(size_t)(d0 + ty + 8 * i) * 256 + kk0 + tx] = t[tx][ty + 8 * i];
}

// ---------------- bf16 MFMA GEMM 128x128: A[M,K] @ Bt[N,K] -> C[M,N] ----------------
template<int EPI, int OBF>
__launch_bounds__(256)
__global__ void gemm_bf16(const short* __restrict__ A, const short* __restrict__ Bt,
                          const float* __restrict__ bias, const float* __restrict__ res,
                          void* __restrict__ Cv, int ldc, int K) {
  __shared__ short As[128][40];
  __shared__ short Bs[128][40];
  int tid = threadIdx.x;
  int n0 = blockIdx.x * 128, m0 = blockIdx.y * 128;
  int lr = tid >> 2;
  int lc = (tid & 3) * 8;
  int wid = tid >> 6, lane = tid & 63;
  int wm = (wid & 1) * 64, wn = (wid >> 1) * 64;
  int quad = lane >> 4, l16 = lane & 15;
  f32x4 acc[4][4];
#pragma unroll
  for (int i = 0; i < 4; i++)
#pragma unroll
    for (int j = 0; j < 4; j++) acc[i][j] = (f32x4){0.f, 0.f, 0.f, 0.f};

  for (int k0 = 0; k0 < K; k0 += 32) {
    int4 av0 = *(const int4*)(A + (size_t)(m0 + lr) * K + k0 + lc);
    int4 av1 = *(const int4*)(A + (size_t)(m0 + lr + 64) * K + k0 + lc);
    int4 bv0 = *(const int4*)(Bt + (size_t)(n0 + lr) * K + k0 + lc);
    int4 bv1 = *(const int4*)(Bt + (size_t)(n0 + lr + 64) * K + k0 + lc);
    __syncthreads();
    *(int4*)&As[lr][lc] = av0;  *(int4*)&As[lr + 64][lc] = av1;
    *(int4*)&Bs[lr][lc] = bv0;  *(int4*)&Bs[lr + 64][lc] = bv1;
    __syncthreads();
    bfrag af[4], bfv[4];
#pragma unroll
    for (int mi = 0; mi < 4; mi++)
      af[mi] = *reinterpret_cast<const bfrag*>(&As[wm + mi * 16 + l16][quad * 8]);
#pragma unroll
    for (int ni = 0; ni < 4; ni++)
      bfv[ni] = *reinterpret_cast<const bfrag*>(&Bs[wn + ni * 16 + l16][quad * 8]);
#pragma unroll
    for (int mi = 0; mi < 4; mi++)
#pragma unroll
      for (int ni = 0; ni < 4; ni++)
        acc[mi][ni] = __builtin_amdgcn_mfma_f32_16x16x32_bf16(af[mi], bfv[ni], acc[mi][ni], 0, 0, 0);
  }

#pragma unroll
  for (int mi = 0; mi < 4; mi++)
#pragma unroll
    for (int ni = 0; ni < 4; ni++) {
      int c = n0 + wn + ni * 16 + l16;
      float bsv = bias[c];
#pragma unroll
      for (int reg = 0; reg < 4; reg++) {
        int r = m0 + wm + mi * 16 + quad * 4 + reg;
        float v = acc[mi][ni][reg] + bsv;
        if (EPI == 1) v = gelu_exact(v);
        if (EPI == 2) v += res[(size_t)r * ldc + c];
        if (OBF) ((short*)Cv)[(size_t)r * ldc + c] = f2b(v);
        else     ((float*)Cv)[(size_t)r * ldc + c] = v;
      }
    }
}

// ---------------- bf16 MFMA GEMM 64x64 ----------------
template<int EPI, int OBF>
__launch_bounds__(256)
__global__ void gemm_bf16_64(const short* __restrict__ A, const short* __restrict__ Bt,
                             const float* __restrict__ bias, const float* __restrict__ res,
                             void* __restrict__ Cv, int ldc, int K) {
  __shared__ short As[64][40];
  __shared__ short Bs[64][40];
  int tid = threadIdx.x;
  int n0 = blockIdx.x * 64, m0 = blockIdx.y * 64;
  int lr = tid >> 2;
  int lc = (tid & 3) * 8;
  int wid = tid >> 6, lane = tid & 63;
  int wm = (wid & 1) * 32, wn = (wid >> 1) * 32;
  int quad = lane >> 4, l16 = lane & 15;
  f32x4 acc[2][2];
#pragma unroll
  for (int i = 0; i < 2; i++)
#pragma unroll
    for (int j = 0; j < 2; j++) acc[i][j] = (f32x4){0.f, 0.f, 0.f, 0.f};

  for (int k0 = 0; k0 < K; k0 += 32) {
    int4 av = *(const int4*)(A + (size_t)(m0 + lr) * K + k0 + lc);
    int4 bv = *(const int4*)(Bt + (size_t)(n0 + lr) * K + k0 + lc);
    __syncthreads();
    *(int4*)&As[lr][lc] = av;
    *(int4*)&Bs[lr][lc] = bv;
    __syncthreads();
    bfrag af[2], bfv[2];
#pragma unroll
    for (int mi = 0; mi < 2; mi++)
      af[mi] = *reinterpret_cast<const bfrag*>(&As[wm + mi * 16 + l16][quad * 8]);
#pragma unroll
    for (int ni = 0; ni < 2; ni++)
      bfv[ni] = *reinterpret_cast<const bfrag*>(&Bs[wn + ni * 16 + l16][quad * 8]);
#pragma unroll
    for (int mi = 0; mi < 2; mi++)
#pragma unroll
      for (int ni = 0; ni < 2; ni++)
        acc[mi][ni] = __builtin_amdgcn_mfma_f32_16x16x32_bf16(af[mi], bfv[ni], acc[mi][ni], 0, 0, 0);
  }

#pragma unroll
  for (int mi = 0; mi < 2; mi++)
#pragma unroll
    for (int ni = 0; ni < 2; ni++) {
      int c = n0 + wn + ni * 16 + l16;
      float bsv = bias[c];
#pragma unroll
      for (int reg = 0; reg < 4; reg++) {
        int r = m0 + wm + mi * 16 + quad * 4 + reg;
        float v = acc[mi][ni][reg] + bsv;
        if (EPI == 1) v = gelu_exact(v);
        if (EPI == 2) v += res[(size_t)r * ldc + c];
        if (OBF) ((short*)Cv)[(size_t)r * ldc + c] = f2b(v);
        else     ((float*)Cv)[(size_t)r * ldc + c] = v;
      }
    }
}

// ---------------- split-K GEMM for w2: A[512,4096] @ Bt[1024,4096], 4 K-slices, f32 partials ----------------
__launch_bounds__(256)
__global__ void gemm_splitk(const short* __restrict__ A, const short* __restrict__ Bt,
                            float* __restrict__ part, int K, int Ks) {
  __shared__ short As[64][40];
  __shared__ short Bs[64][40];
  int tid = threadIdx.x;
  int n0 = blockIdx.x * 64, m0 = blockIdx.y * 64, s = blockIdx.z;
  int kbase = s * Ks;
  int lr = tid >> 2;
  int lc = (tid & 3) * 8;
  int wid = tid >> 6, lane = tid & 63;
  int wm = (wid & 1) * 32, wn = (wid >> 1) * 32;
  int quad = lane >> 4, l16 = lane & 15;
  f32x4 acc[2][2];
#pragma unroll
  for (int i = 0; i < 2; i++)
#pragma unroll
    for (int j = 0; j < 2; j++) acc[i][j] = (f32x4){0.f, 0.f, 0.f, 0.f};

  for (int k0 = kbase; k0 < kbase + Ks; k0 += 32) {
    int4 av = *(const int4*)(A + (size_t)(m0 + lr) * K + k0 + lc);
    int4 bv = *(const int4*)(Bt + (size_t)(n0 + lr) * K + k0 + lc);
    __syncthreads();
    *(int4*)&As[lr][lc] = av;
    *(int4*)&Bs[lr][lc] = bv;
    __syncthreads();
    bfrag af[2], bfv[2];
#pragma unroll
    for (int mi = 0; mi < 2; mi++)
      af[mi] = *reinterpret_cast<const bfrag*>(&As[wm + mi * 16 + l16][quad * 8]);
#pragma unroll
    for (int ni = 0; ni < 2; ni++)
      bfv[ni] = *reinterpret_cast<const bfrag*>(&Bs[wn + ni * 16 + l16][quad * 8]);
#pragma unroll
    for (int mi = 0; mi < 2; mi++)
#pragma unroll
      for (int ni = 0; ni < 2; ni++)
        acc[mi][ni] = __builtin_amdgcn_mfma_f32_16x16x32_bf16(af[mi], bfv[ni], acc[mi][ni], 0, 0, 0);
  }

#pragma unroll
  for (int mi = 0; mi < 2; mi++)
#pragma unroll
    for (int ni = 0; ni < 2; ni++) {
      int c = n0 + wn + ni * 16 + l16;
#pragma unroll
      for (int reg = 0; reg < 4; reg++) {
        int r = m0 + wm + mi * 16 + quad * 4 + reg;
        part[(size_t)s * 524288 + (size_t)r * 1024 + c] = acc[mi][ni][reg];
      }
    }
}

// reduce 4 partials + bias + residual -> patches (f32)
__global__ void w2red_kernel(const float* __restrict__ part, const float* __restrict__ bias,
                             float* __restrict__ patches) {
  int i = (blockIdx.x * 256 + threadIdx.x) * 4;  // over 512*1024 elems
  float4 v = *(const float4*)(part + i);
#pragma unroll
  for (int s = 1; s < 4; s++) {
    float4 p = *(const float4*)(part + (size_t)s * 524288 + i);
    v.x += p.x; v.y += p.y; v.z += p.z; v.w += p.w;
  }
  int c = i & 1023;
  float4 bv = *(const float4*)(bias + c);
  float4 rv = *(const float4*)(patches + i);
  v.x += bv.x + rv.x; v.y += bv.y + rv.y; v.z += bv.z + rv.z; v.w += bv.w + rv.w;
  *(float4*)(patches + i) = v;
}

// ---------------- global self-attn MFMA: nh=16, dh=64, P=256, causal ----------------
// grid (4, B*16); 4 waves; wave owns 16 q-rows. K/V^T staged via LDS chunks of 64 keys.
__launch_bounds__(256)
__global__ void attn_global3(const short* __restrict__ qkvb, const short* __restrict__ vtg,
                             short* __restrict__ outp) {
  int qt = blockIdx.x;
  int bh = blockIdx.y; int h = bh & 15, b = bh >> 4;
  int tid = threadIdx.x;
  int wid = tid >> 6, lane = tid & 63;
  int quad = lane >> 4, l16 = lane & 15;
  int q0 = qt * 64 + wid * 16;
  __shared__ short KV[64 * 72];       // stride 72 shorts -> balanced banks
  __shared__ short Pl[4][16][264];
  const short* qrow = qkvb + ((size_t)(b * Pn + q0 + l16)) * 3072 + h * 64 + quad * 8;
  bfrag qf[2];
#pragma unroll
  for (int kd = 0; kd < 2; kd++) qf[kd] = *(const bfrag*)(qrow + kd * 32);
  f32x4 sacc[16];
#pragma unroll
  for (int n = 0; n < 16; n++) sacc[n] = (f32x4){0.f, 0.f, 0.f, 0.f};
  int cr = tid >> 2, cc = (tid & 3) * 16;
#pragma unroll
  for (int kc = 0; kc < 4; kc++) {
    if (kc <= qt) {       // block-uniform guard (causal skip)
      const short* ksrc = qkvb + ((size_t)(b * Pn + kc * 64 + cr)) * 3072 + 1024 + h * 64 + cc;
      int4 v0 = *(const int4*)(ksrc);
      int4 v1 = *(const int4*)(ksrc + 8);
      __syncthreads();
      *(int4*)&KV[cr * 72 + cc] = v0;
      *(int4*)&KV[cr * 72 + cc + 8] = v1;
      __syncthreads();
#pragma unroll
      for (int n = 0; n < 4; n++)
#pragma unroll
        for (int kd = 0; kd < 2; kd++) {
          bfrag kf = *(const bfrag*)&KV[(n * 16 + l16) * 72 + kd * 32 + quad * 8];
          sacc[kc * 4 + n] = __builtin_amdgcn_mfma_f32_16x16x32_bf16(qf[kd], kf, sacc[kc * 4 + n], 0, 0, 0);
        }
    }
  }
  int nfr = (qt + 1) * 4;
  const float scale = 0.125f;
  float mx[4] = {-1e30f, -1e30f, -1e30f, -1e30f};
#pragma unroll
  for (int n = 0; n < 16; n++) {
    if (n < nfr) {
      int col = n * 16 + l16;
#pragma unroll
      for (int r = 0; r < 4; r++)
        if (col <= q0 + quad * 4 + r) mx[r] = fmaxf(mx[r], sacc[n][r]);
    }
  }
#pragma unroll
  for (int off = 1; off < 16; off <<= 1)
#pragma unroll
    for (int r = 0; r < 4; r++) mx[r] = fmaxf(mx[r], __shfl_xor(mx[r], off));
  float ls[4] = {0.f, 0.f, 0.f, 0.f};
#pragma unroll
  for (int n = 0; n < 16; n++) {
    if (n < nfr) {
      int col = n * 16 + l16;
#pragma unroll
      for (int r = 0; r < 4; r++) {
        float p = (col <= q0 + quad * 4 + r) ? __expf((sacc[n][r] - mx[r]) * scale) : 0.f;
        Pl[wid][quad * 4 + r][col] = f2b(p);
        ls[r] += p;
      }
    }
  }
#pragma unroll
  for (int off = 1; off < 16; off <<= 1)
#pragma unroll
    for (int r = 0; r < 4; r++) ls[r] += __shfl_xor(ls[r], off);
  float rl[4];
#pragma unroll
  for (int r = 0; r < 4; r++) rl[r] = 1.0f / ls[r];

  f32x4 oacc[4];
#pragma unroll
  for (int n = 0; n < 4; n++) oacc[n] = (f32x4){0.f, 0.f, 0.f, 0.f};
#pragma unroll
  for (int kc = 0; kc < 4; kc++) {
    if (kc <= qt) {
      const short* vsrc = vtg + (size_t)bh * 64 * 256 + cr * 256 + kc * 64 + cc;
      int4 v0 = *(const int4*)(vsrc);
      int4 v1 = *(const int4*)(vsrc + 8);
      __syncthreads();
      *(int4*)&KV[cr * 72 + cc] = v0;
      *(int4*)&KV[cr * 72 + cc + 8] = v1;
      __syncthreads();
#pragma unroll
      for (int kk = 0; kk < 2; kk++) {
        bfrag pa = *(const bfrag*)&Pl[wid][l16][kc * 64 + kk * 32 + quad * 8];
#pragma unroll
        for (int n = 0; n < 4; n++) {
          bfrag vf = *(const bfrag*)&KV[(n * 16 + l16) * 72 + kk * 32 + quad * 8];
          oacc[n] = __builtin_amdgcn_mfma_f32_16x16x32_bf16(pa, vf, oacc[n], 0, 0, 0);
        }
      }
    }
  }
#pragma unroll
  for (int n = 0; n < 4; n++)
#pragma unroll
    for (int r = 0; r < 4; r++)
      outp[(size_t)(b * Pn + q0 + quad * 4 + r) * Hdim + h * 64 + n * 16 + l16] = f2b(oacc[n][r] * rl[r]);
}

// ---------------- cross-attn MFMA v4: LDS-staged K/V chunks. nh=8, dh=128, Lq=4096, Lk=256 ----------------
// grid (64, 16); 4 waves; wave owns 16 q-rows.
__launch_bounds__(256)
__global__ void attn_cross4(const short* __restrict__ q, const short* __restrict__ k,
                            const short* __restrict__ vt, short* __restrict__ outp) {
  int bh = blockIdx.y; int h = bh & 7, b = bh >> 3;
  int tid = threadIdx.x;
  int wid = tid >> 6, lane = tid & 63;
  int quad = lane >> 4, l16 = lane & 15;
  int q0 = blockIdx.x * 64 + wid * 16;
  __shared__ short KV[9216];          // K view: [64][136]; V view: [128][72]
  __shared__ short Pl[4][16][264];
  const short* qrow = q + ((size_t)(b * Slen + q0 + l16)) * Hdim + h * 128 + quad * 8;
  bfrag qf[4];
#pragma unroll
  for (int kd = 0; kd < 4; kd++) qf[kd] = *(const bfrag*)(qrow + kd * 32);
  f32x4 sacc[16];
#pragma unroll
  for (int n = 0; n < 16; n++) sacc[n] = (f32x4){0.f, 0.f, 0.f, 0.f};

  int cr4 = tid >> 2, cc4 = (tid & 3) * 32;   // K coop: 64 rows x 128 cols
#pragma unroll
  for (int kc = 0; kc < 4; kc++) {
    const short* ksrc = k + ((size_t)(b * Pn + kc * 64 + cr4)) * Hdim + h * 128 + cc4;
    int4 v0 = *(const int4*)(ksrc);
    int4 v1 = *(const int4*)(ksrc + 8);
    int4 v2 = *(const int4*)(ksrc + 16);
    int4 v3 = *(const int4*)(ksrc + 24);
    __syncthreads();
    *(int4*)&KV[cr4 * 136 + cc4]      = v0;
    *(int4*)&KV[cr4 * 136 + cc4 + 8]  = v1;
    *(int4*)&KV[cr4 * 136 + cc4 + 16] = v2;
    *(int4*)&KV[cr4 * 136 + cc4 + 24] = v3;
    __syncthreads();
#pragma unroll
    for (int n = 0; n < 4; n++)
#pragma unroll
      for (int kd = 0; kd < 4; kd++) {
        bfrag kf = *(const bfrag*)&KV[(n * 16 + l16) * 136 + kd * 32 + quad * 8];
        sacc[kc * 4 + n] = __builtin_amdgcn_mfma_f32_16x16x32_bf16(qf[kd], kf, sacc[kc * 4 + n], 0, 0, 0);
      }
  }

  const float scale = 0.088388347648318447f;
  float mx[4] = {-1e30f, -1e30f, -1e30f, -1e30f};
#pragma unroll
  for (int n = 0; n < 16; n++)
#pragma unroll
    for (int r = 0; r < 4; r++) mx[r] = fmaxf(mx[r], sacc[n][r]);
#pragma unroll
  for (int off = 1; off < 16; off <<= 1)
#pragma unroll
    for (int r = 0; r < 4; r++) mx[r] = fmaxf(mx[r], __shfl_xor(mx[r], off));
  float ls[4] = {0.f, 0.f, 0.f, 0.f};
#pragma unroll
  for (int n = 0; n < 16; n++)
#pragma unroll
    for (int r = 0; r < 4; r++) {
      float p = __expf((sacc[n][r] - mx[r]) * scale);
      Pl[wid][quad * 4 + r][n * 16 + l16] = f2b(p);
      ls[r] += p;
    }
#pragma unroll
  for (int off = 1; off < 16; off <<= 1)
#pragma unroll
    for (int r = 0; r < 4; r++) ls[r] += __shfl_xor(ls[r], off);
  float rl[4];
#pragma unroll
  for (int r = 0; r < 4; r++) rl[r] = 1.0f / ls[r];

  f32x4 oacc[8];
#pragma unroll
  for (int n = 0; n < 8; n++) oacc[n] = (f32x4){0.f, 0.f, 0.f, 0.f};
  int cr2 = tid >> 1, cc2 = (tid & 1) * 32;   // V coop: 128 rows x 64 cols
#pragma unroll
  for (int kc = 0; kc < 4; kc++) {
    const short* vsrc = vt + (size_t)bh * 32768 + cr2 * 256 + kc * 64 + cc2;
    int4 v0 = *(const int4*)(vsrc);
    int4 v1 = *(const int4*)(vsrc + 8);
    int4 v2 = *(const int4*)(vsrc + 16);
    int4 v3 = *(const int4*)(vsrc + 24);
    __syncthreads();
    *(int4*)&KV[cr2 * 72 + cc2]      = v0;
    *(int4*)&KV[cr2 * 72 + cc2 + 8]  = v1;
    *(int4*)&KV[cr2 * 72 + cc2 + 16] = v2;
    *(int4*)&KV[cr2 * 72 + cc2 + 24] = v3;
    __syncthreads();
#pragma unroll
    for (int kk = 0; kk < 2; kk++) {
      bfrag pa = *(const bfrag*)&Pl[wid][l16][kc * 64 + kk * 32 + quad * 8];
#pragma unroll
      for (int n = 0; n < 8; n++) {
        bfrag vf = *(const bfrag*)&KV[(n * 16 + l16) * 72 + kk * 32 + quad * 8];
        oacc[n] = __builtin_amdgcn_mfma_f32_16x16x32_bf16(pa, vf, oacc[n], 0, 0, 0);
      }
    }
  }
#pragma unroll
  for (int n = 0; n < 8; n++)
#pragma unroll
    for (int r = 0; r < 4; r++)
      outp[(size_t)(b * Slen + q0 + quad * 4 + r) * Hdim + h * 128 + n * 16 + l16] = f2b(oacc[n][r] * rl[r]);
}

extern "C" void kernel_launch(void* const* d_in, const int* in_sizes, int n_in,
                              void* d_out, int out_size, void* d_ws, size_t ws_size,
                              hipStream_t stream) {
  const int*   byte_seq = (const int*)d_in[0];
  const int*   pbound   = (const int*)d_in[1];
  const float* emb      = (const float*)d_in[2];
  const float* g_ln1_g  = (const float*)d_in[3];
  const float* g_ln1_b  = (const float*)d_in[4];
  const float* g_wqkv   = (const float*)d_in[5];
  const float* g_bqkv   = (const float*)d_in[6];
  const float* g_wo     = (const float*)d_in[7];
  const float* g_bo     = (const float*)d_in[8];
  const float* g_ln2_g  = (const float*)d_in[9];
  const float* g_ln2_b  = (const float*)d_in[10];
  const float* g_w1     = (const float*)d_in[11];
  const float* g_b1     = (const float*)d_in[12];
  const float* g_w2     = (const float*)d_in[13];
  const float* g_b2     = (const float*)d_in[14];
  const float* fn_g     = (const float*)d_in[15];
  const float* fn_b     = (const float*)d_in[16];
  const float* ca_ln_g  = (const float*)d_in[17];
  const float* ca_ln_b  = (const float*)d_in[18];
  const float* ca_wqkv  = (const float*)d_in[19];
  const float* ca_bqkv  = (const float*)d_in[20];
  const float* ca_wo    = (const float*)d_in[21];
  const float* ca_bo    = (const float*)d_in[22];
  const float* head_w   = (const float*)d_in[23];
  const float* head_b   = (const float*)d_in[24];
  float* out = (float*)d_out;

  // ---- workspace layout ----
  float* x       = (float*)d_ws;                 // 8388608 f32
  float* patches = x + 8388608;                  // 524288
  float* vbuf    = patches + 524288;             // 524288
  float* w2part  = vbuf + 524288;                // 2097152 (4 x 512x1024 partials)
  int*   pid     = (int*)(w2part + 2097152);     // 8192 ints
  short* nbuf    = (short*)(pid + 8192);         // 524288 bf16
  short* attn_o  = nbuf + 524288;                // 524288
  short* mid     = attn_o + 524288;              // 2097152
  short* qn      = mid + 2097152;                // 8388608 (LN(x); reused as caout)
  short* qb      = qn + 8388608;                 // 8388608
  short* xb      = qb + 8388608;                 // 8388608
  short* kb      = xb + 8388608;                 // 524288 (cross K bf16)
  short* vt      = kb + 524288;                  // 524288 (cross V^T bf16)
  short* qkvb    = vt + 524288;                  // 1572864 (layer qkv bf16)
  short* vtg     = qkvb + 1572864;               // 524288 (global V^T bf16)
  short* wqkv_t  = vtg + 524288;                 // 12582912
  short* wo_t    = wqkv_t + 12582912;            // 4194304
  short* w1_t    = wo_t + 4194304;               // 16777216
  short* w2_t    = w1_t + 16777216;              // 16777216
  short* caq_t   = w2_t + 16777216;              // 1048576
  short* cak_t   = caq_t + 1048576;              // 1048576
  short* cav_t   = cak_t + 1048576;              // 1048576
  short* cawo_t  = cav_t + 1048576;              // 1048576
  short* head_t  = cawo_t + 1048576;             // 262144
  short* caout   = qn;                           // alias (qn dead after q-proj)

  // 1. byte embeddings, patch ids, pooling
  embed_kernel<<<Bsz * Slen, 256, 0, stream>>>(byte_seq, emb, x);
  pid_kernel<<<(Bsz * Slen) / 256, 256, 0, stream>>>(pbound, pid);
  pool_kernel<<<Bsz * Pn, 256, 0, stream>>>(x, pid, patches);

  // 2. weight convert + transpose to bf16 [N,K]
  wconv_kernel<<<dim3(96, 32, 4), 256, 0, stream>>>(g_wqkv, wqkv_t, 3072, 1024, 3145728, 3145728);
  wconv_kernel<<<dim3(32, 32, 4), 256, 0, stream>>>(g_wo, wo_t, 1024, 1024, 1048576, 1048576);
  wconv_kernel<<<dim3(128, 32, 4), 256, 0, stream>>>(g_w1, w1_t, 4096, 1024, 4194304, 4194304);
  wconv_kernel<<<dim3(32, 128, 4), 256, 0, stream>>>(g_w2, w2_t, 1024, 4096, 4194304, 4194304);
  wconv_kernel<<<dim3(32, 32, 3), 256, 0, stream>>>(ca_wqkv, caq_t, 3072, 1024, 1024, 1048576);
  wconv_kernel<<<dim3(32, 32, 1), 256, 0, stream>>>(ca_wo, cawo_t, 1024, 1024, 0, 0);
  wconv_kernel<<<dim3(8, 32, 1), 256, 0, stream>>>(head_w, head_t, 256, 1024, 0, 0);

  // 3. global transformer layers
  for (int l = 0; l < NLAY; ++l) {
    ln_kernel<1><<<Bsz * Pn, 256, 0, stream>>>(patches, g_ln1_g + l * Hdim, g_ln1_b + l * Hdim, nbuf);
    gemm_bf16_64<0, 1><<<dim3(48, 8), 256, 0, stream>>>(
        nbuf, wqkv_t + (size_t)l * 3145728, g_bqkv + l * 3072, nullptr, qkvb, 3072, 1024);
    vtg_kernel<<<dim3(8, 2, 32), 256, 0, stream>>>(qkvb, vtg);
    attn_global3<<<dim3(4, 32), 256, 0, stream>>>(qkvb, vtg, attn_o);
    gemm_bf16_64<2, 0><<<dim3(16, 8), 256, 0, stream>>>(
        attn_o, wo_t + (size_t)l * 1048576, g_bo + l * Hdim, patches, patches, 1024, 1024);
    ln_kernel<1><<<Bsz * Pn, 256, 0, stream>>>(patches, g_ln2_g + l * Hdim, g_ln2_b + l * Hdim, nbuf);
    gemm_bf16_64<1, 1><<<dim3(64, 8), 256, 0, stream>>>(
        nbuf, w1_t + (size_t)l * 4194304, g_b1 + l * 4096, nullptr, mid, 4096, 1024);
    gemm_splitk<<<dim3(16, 8, 4), 256, 0, stream>>>(
        mid, w2_t + (size_t)l * 4194304, w2part, 4096, 1024);
    w2red_kernel<<<512, 256, 0, stream>>>(w2part, g_b2 + l * Hdim, patches);
  }

  // 4. final norm (f32, in-place), then cross-attn LN of patches -> bf16
  ln_kernel<0><<<Bsz * Pn, 256, 0, stream>>>(patches, fn_g, fn_b, patches);
  ln_kernel<1><<<Bsz * Pn, 256, 0, stream>>>(patches, ca_ln_g, ca_ln_b, nbuf);

  // 5. k (bf16 out), v (f32 out -> transposed bf16)
  gemm_bf16_64<0, 1><<<dim3(16, 8), 256, 0, stream>>>(
      nbuf, cak_t, ca_bqkv + 1024, nullptr, kb, 1024, 1024);
  gemm_bf16_64<0, 0><<<dim3(16, 8), 256, 0, stream>>>(
      nbuf, cav_t, ca_bqkv + 2048, nullptr, vbuf, 1024, 1024);
  vt_kernel<<<dim3(8, 4, 16), 256, 0, stream>>>(vbuf, vt);

  // 6. q projection from LN(x) -> bf16
  ln_kernel<1><<<Bsz * Slen, 256, 0, stream>>>(x, ca_ln_g, ca_ln_b, qn);
  gemm_bf16<0, 1><<<dim3(8, 64), 256, 0, stream>>>(
      qn, caq_t, ca_bqkv, nullptr, qb, 1024, 1024);

  // 7. MFMA cross attention (qn dead; caout aliases it)
  attn_cross4<<<dim3(64, 16), 256, 0, stream>>>(qb, kb, vt, caout);

  // 8. output projection + residual -> xb (bf16, feeds head)
  gemm_bf16<2, 1><<<dim3(8, 64), 256, 0, stream>>>(
      caout, cawo_t, ca_bo, x, xb, 1024, 1024);

  // 9. head
  gemm_bf16_64<0, 0><<<dim3(4, 128), 256, 0, stream>>>(
      xb, head_t, head_b, nullptr, out, 256, 1024);
}